// Round 3
// baseline (615.071 us; speedup 1.0000x reference)
//
#include <hip/hip_runtime.h>
#include <math.h>

#define B_ 64
#define N_ 512
#define DIM_ 128
#define E_ 16
#define G_ 32
#define TOPK_ 4
#define HID_ 512

constexpr int BN_ROWS = B_ * N_;  // 32768

// ---- workspace layout (floats) ----
constexpr size_t OFF_XN  = 0;                                     // xn / xn2 (reused)
constexpr size_t OFF_X1  = OFF_XN + (size_t)BN_ROWS * DIM_;       // x + attn
constexpr size_t OFF_RT  = OFF_X1 + (size_t)BN_ROWS * DIM_;       // dense route weights [B,N,16]
constexpr size_t OFF_A1  = OFF_RT + (size_t)BN_ROWS * E_;         // softmax(E1) [2,E,N,G]
constexpr size_t OFF_A2  = OFF_A1 + (size_t)2 * E_ * N_ * G_;     // softmax(E2) [2,E,G,N]
constexpr size_t OFF_Y   = OFF_A2 + (size_t)2 * E_ * G_ * N_;     // Y [B,2,512,128]
constexpr size_t OFF_H   = OFF_Y  + (size_t)B_ * 2 * 512 * DIM_;  // h [B*N,512]
constexpr size_t OFF_LAM = OFF_H  + (size_t)BN_ROWS * HID_;       // lambda_full scalar

// ---------------- lambda_full ----------------
__global__ void k_lambda(const float* __restrict__ lq1, const float* __restrict__ lk1,
                         const float* __restrict__ lq2, const float* __restrict__ lk2,
                         float lam_init, float* __restrict__ lam_out) {
    int l = threadIdx.x;  // 64 threads
    float s1 = lq1[l] * lk1[l] + lq1[l + 64] * lk1[l + 64];
    float s2 = lq2[l] * lk2[l] + lq2[l + 64] * lk2[l + 64];
    for (int off = 32; off; off >>= 1) {
        s1 += __shfl_xor(s1, off);
        s2 += __shfl_xor(s2, off);
    }
    if (l == 0) lam_out[0] = -(expf(s1) - expf(s2) + lam_init);
}

// ---------------- rmsnorm (p<0 variant: rms = ||v||/sqrt(d), denom = rms+eps) ----------------
__global__ void k_rmsnorm(const float* __restrict__ in, const float* __restrict__ scale,
                          float* __restrict__ out) {
    int row  = blockIdx.x * 4 + (threadIdx.x >> 6);
    int lane = threadIdx.x & 63;
    const float2* p = (const float2*)(in + (size_t)row * DIM_);
    float2 v = p[lane];
    float ss = v.x * v.x + v.y * v.y;
    for (int off = 32; off; off >>= 1) ss += __shfl_xor(ss, off);
    float denom = sqrtf(ss * (1.0f / DIM_)) + 1e-8f;
    float inv = 1.0f / denom;
    float2 s = ((const float2*)scale)[lane];
    float2 o;
    o.x = v.x * inv * s.x;
    o.y = v.y * inv * s.y;
    ((float2*)(out + (size_t)row * DIM_))[lane] = o;
}

// ---------------- routing: logits -> sigmoid -> top-4 -> normalized dense route ----------------
// NOTE: topk indices are written as FLOAT values — the harness reads the whole
// d_out buffer as float32 and splits it; int bit-patterns read back as ~0.
__global__ void k_route(const float* __restrict__ xn, const float* __restrict__ Wr,
                        const float* __restrict__ br, const float* __restrict__ bias,
                        float* __restrict__ route, float* __restrict__ topk_out) {
    int row  = blockIdx.x * 4 + (threadIdx.x >> 6);
    int lane = threadIdx.x & 63;
    int e = lane & 15, chunk = lane >> 4;
    const float* xr = xn + (size_t)row * DIM_;
    float acc = 0.f;
#pragma unroll
    for (int j = 0; j < 32; ++j) {
        int d = chunk * 32 + j;
        acc += xr[d] * Wr[d * E_ + e];
    }
    acc += __shfl_xor(acc, 16);
    acc += __shfl_xor(acc, 32);
    float gate = 1.0f / (1.0f + expf(-(acc + br[e])));
    // gather all 16 gates into registers on every lane
    float g[16];
#pragma unroll
    for (int i = 0; i < 16; ++i) g[i] = __shfl(gate, i);
    float bv = bias[0];
    unsigned sel = 0;
    int idx[4];
    float ssum = 0.f;
#pragma unroll
    for (int t = 0; t < 4; ++t) {
        float best = -1e30f;
        int bi = 0;
        float bg = 0.f;
#pragma unroll
        for (int i = 0; i < 16; ++i) {
            if (!((sel >> i) & 1)) {
                float cv = g[i] + bv;
                if (cv > best) { best = cv; bi = i; bg = g[i]; }  // strict > : lower index wins ties (lax.top_k)
            }
        }
        sel |= 1u << bi;
        idx[t] = bi;
        ssum += bg;
    }
    float inv = 1.0f / ssum;
    if (lane < 16) {
        float rw = ((sel >> e) & 1) ? gate * inv : 0.0f;
        route[(size_t)row * E_ + e] = rw;
    }
    if (lane < 4) topk_out[(size_t)row * TOPK_ + lane] = (float)idx[lane];
}

// ---------------- softmax over G=32 (A1 = softmax(E1, axis=-1)) ----------------
__global__ void k_softmax_g(const float* __restrict__ E1, float* __restrict__ A1n) {
    int row = blockIdx.x * 8 + (threadIdx.x >> 5);  // 2*16*512 = 16384 rows
    int l   = threadIdx.x & 31;
    float v = E1[(size_t)row * 32 + l];
    float m = v;
    for (int off = 16; off; off >>= 1) m = fmaxf(m, __shfl_xor(m, off));
    float ev = expf(v - m);
    float s = ev;
    for (int off = 16; off; off >>= 1) s += __shfl_xor(s, off);
    A1n[(size_t)row * 32 + l] = ev / s;
}

// ---------------- softmax over N=512 (A2 = softmax(E2, axis=-1)) ----------------
__global__ void k_softmax_n(const float* __restrict__ E2, float* __restrict__ A2n) {
    int row = blockIdx.x * 4 + (threadIdx.x >> 6);  // 2*16*32 = 1024 rows
    int l   = threadIdx.x & 63;
    const float* p = E2 + (size_t)row * 512;
    float v[8];
    float m = -1e30f;
#pragma unroll
    for (int j = 0; j < 8; ++j) { v[j] = p[l + j * 64]; m = fmaxf(m, v[j]); }
    for (int off = 32; off; off >>= 1) m = fmaxf(m, __shfl_xor(m, off));
    float s = 0.f;
#pragma unroll
    for (int j = 0; j < 8; ++j) { v[j] = expf(v[j] - m); s += v[j]; }
    for (int off = 32; off; off >>= 1) s += __shfl_xor(s, off);
    float inv = 1.0f / s;
    float* q = A2n + (size_t)row * 512;
#pragma unroll
    for (int j = 0; j < 8; ++j) q[l + j * 64] = v[j] * inv;
}

// ---------------- Y[b,e] = A2n[e] ([512,512]) @ xn[b] ([512,128]) ----------------
__global__ __launch_bounds__(256) void k_gemm_y(const float* __restrict__ A2n,
                                                const float* __restrict__ xn,
                                                float* __restrict__ Y) {
    constexpr int BM = 128, BN = 128, BK = 32;
    __shared__ float As[BK][BM + 4];
    __shared__ float Bs[BK][BN + 4];
    int be = blockIdx.y;
    int e = be & 1, b = be >> 1;
    int m0 = blockIdx.x * BM;
    const float* A  = A2n + (size_t)e * 512 * 512;
    const float* Bx = xn + (size_t)b * 512 * 128;
    int tid = threadIdx.x;
    int tx = tid & 15, ty = tid >> 4;
    float acc[8][8] = {};
    for (int t = 0; t < 512 / BK; ++t) {
        int k0 = t * BK;
        __syncthreads();
#pragma unroll
        for (int r = 0; r < 4; ++r) {
            int idx = tid + r * 256;
            int row = idx >> 3, cv = idx & 7;
            float4 v = *(const float4*)(A + (size_t)(m0 + row) * 512 + k0 + cv * 4);
            As[cv * 4 + 0][row] = v.x; As[cv * 4 + 1][row] = v.y;
            As[cv * 4 + 2][row] = v.z; As[cv * 4 + 3][row] = v.w;
        }
#pragma unroll
        for (int r = 0; r < 4; ++r) {
            int idx = tid + r * 256;
            int row = idx >> 5, cv = idx & 31;
            *(float4*)&Bs[row][cv * 4] = *(const float4*)(Bx + (size_t)(k0 + row) * 128 + cv * 4);
        }
        __syncthreads();
#pragma unroll
        for (int kk = 0; kk < BK; ++kk) {
            float a_[8], b_[8];
#pragma unroll
            for (int i = 0; i < 8; ++i) a_[i] = As[kk][ty * 8 + i];
#pragma unroll
            for (int j = 0; j < 8; ++j) b_[j] = Bs[kk][tx * 8 + j];
#pragma unroll
            for (int i = 0; i < 8; ++i)
#pragma unroll
                for (int j = 0; j < 8; ++j) acc[i][j] += a_[i] * b_[j];
        }
    }
    float* C = Y + (size_t)be * 512 * 128;
#pragma unroll
    for (int i = 0; i < 8; ++i) {
        int m = m0 + ty * 8 + i;
#pragma unroll
        for (int j = 0; j < 8; j += 4) {
            float4 v = {acc[i][j], acc[i][j + 1], acc[i][j + 2], acc[i][j + 3]};
            *(float4*)(C + (size_t)m * 128 + tx * 8 + j) = v;
        }
    }
}

// ---------------- attn + residual: x1[b] = x[b] + W[b] ([512,1024]) @ Ycat[b] ([1024,128]) ----------------
// W[b, e*512 + k*32 + d, i] built on the fly = route[b,i,k] * A1n[e,k,i,d] * (e ? lambda_full : 1)
__global__ __launch_bounds__(256) void k_attn(const float* __restrict__ A1n,
                                              const float* __restrict__ route,
                                              const float* __restrict__ Y,
                                              const float* __restrict__ x,
                                              const float* __restrict__ lam_p,
                                              float* __restrict__ x1) {
    constexpr int BM = 128, BN = 128, BK = 32;
    __shared__ float As[BK][BM + 4];
    __shared__ float Bs[BK][BN + 4];
    int b = blockIdx.y;
    int m0 = blockIdx.x * BM;
    float lam = lam_p[0];
    int tid = threadIdx.x;
    int tx = tid & 15, ty = tid >> 4;
    float acc[8][8] = {};
    for (int t = 0; t < 32; ++t) {  // K = 1024, one (e,k) per step
        int e = t >> 4, k = t & 15;
        float esc = e ? lam : 1.0f;
        const float* Ab = A1n + ((size_t)(e * 16 + k) * 512) * 32;   // [i][d]
        const float* Bb = Y + ((size_t)b * 1024 + (size_t)t * 32) * 128;
        __syncthreads();
#pragma unroll
        for (int r = 0; r < 4; ++r) {
            int idx = tid + r * 256;
            int row = idx >> 3, cv = idx & 7;
            int gi = m0 + row;
            float rw = route[((size_t)b * 512 + gi) * E_ + k] * esc;
            float4 v = *(const float4*)(Ab + (size_t)gi * 32 + cv * 4);
            As[cv * 4 + 0][row] = v.x * rw; As[cv * 4 + 1][row] = v.y * rw;
            As[cv * 4 + 2][row] = v.z * rw; As[cv * 4 + 3][row] = v.w * rw;
        }
#pragma unroll
        for (int r = 0; r < 4; ++r) {
            int idx = tid + r * 256;
            int row = idx >> 5, cv = idx & 31;
            *(float4*)&Bs[row][cv * 4] = *(const float4*)(Bb + (size_t)row * 128 + cv * 4);
        }
        __syncthreads();
#pragma unroll
        for (int kk = 0; kk < BK; ++kk) {
            float a_[8], b_[8];
#pragma unroll
            for (int i = 0; i < 8; ++i) a_[i] = As[kk][ty * 8 + i];
#pragma unroll
            for (int j = 0; j < 8; ++j) b_[j] = Bs[kk][tx * 8 + j];
#pragma unroll
            for (int i = 0; i < 8; ++i)
#pragma unroll
                for (int j = 0; j < 8; ++j) acc[i][j] += a_[i] * b_[j];
        }
    }
#pragma unroll
    for (int i = 0; i < 8; ++i) {
        int gi = m0 + ty * 8 + i;
        const float* xr = x + ((size_t)b * 512 + gi) * 128;
        float* o = x1 + ((size_t)b * 512 + gi) * 128;
#pragma unroll
        for (int j = 0; j < 8; j += 4) {
            float4 xv = *(const float4*)(xr + tx * 8 + j);
            float4 v = {acc[i][j] + xv.x, acc[i][j + 1] + xv.y,
                        acc[i][j + 2] + xv.z, acc[i][j + 3] + xv.w};
            *(float4*)(o + tx * 8 + j) = v;
        }
    }
}

// ---------------- FFN stage 1: h = silu(xn2@W1+b1) * (xn2@W2+b2) ----------------
__global__ __launch_bounds__(256) void k_ffn1(const float* __restrict__ xn2,
                                              const float* __restrict__ W1, const float* __restrict__ b1,
                                              const float* __restrict__ W2, const float* __restrict__ b2,
                                              float* __restrict__ h) {
    constexpr int BM = 128, BN = 64, BK = 32;
    __shared__ float As[BK][BM + 4];
    __shared__ float B1s[BK][BN + 4];
    __shared__ float B2s[BK][BN + 4];
    int m0 = blockIdx.y * BM;
    int n0 = blockIdx.x * BN;
    int tid = threadIdx.x;
    int tx = tid & 15, ty = tid >> 4;
    float acc1[8][4] = {}, acc2[8][4] = {};
    for (int t = 0; t < 4; ++t) {  // K = 128
        int k0 = t * BK;
        __syncthreads();
#pragma unroll
        for (int r = 0; r < 4; ++r) {
            int idx = tid + r * 256;
            int row = idx >> 3, cv = idx & 7;
            float4 v = *(const float4*)(xn2 + (size_t)(m0 + row) * 128 + k0 + cv * 4);
            As[cv * 4 + 0][row] = v.x; As[cv * 4 + 1][row] = v.y;
            As[cv * 4 + 2][row] = v.z; As[cv * 4 + 3][row] = v.w;
        }
#pragma unroll
        for (int r = 0; r < 2; ++r) {
            int idx = tid + r * 256;
            int row = idx >> 4, cv = idx & 15;
            *(float4*)&B1s[row][cv * 4] = *(const float4*)(W1 + (size_t)(k0 + row) * 512 + n0 + cv * 4);
            *(float4*)&B2s[row][cv * 4] = *(const float4*)(W2 + (size_t)(k0 + row) * 512 + n0 + cv * 4);
        }
        __syncthreads();
#pragma unroll
        for (int kk = 0; kk < BK; ++kk) {
            float a_[8], p_[4], q_[4];
#pragma unroll
            for (int i = 0; i < 8; ++i) a_[i] = As[kk][ty * 8 + i];
#pragma unroll
            for (int j = 0; j < 4; ++j) { p_[j] = B1s[kk][tx * 4 + j]; q_[j] = B2s[kk][tx * 4 + j]; }
#pragma unroll
            for (int i = 0; i < 8; ++i)
#pragma unroll
                for (int j = 0; j < 4; ++j) {
                    acc1[i][j] += a_[i] * p_[j];
                    acc2[i][j] += a_[i] * q_[j];
                }
        }
    }
#pragma unroll
    for (int i = 0; i < 8; ++i) {
        int m = m0 + ty * 8 + i;
        float o_[4];
#pragma unroll
        for (int j = 0; j < 4; ++j) {
            int n = n0 + tx * 4 + j;
            float aa = acc1[i][j] + b1[n];
            float bb = acc2[i][j] + b2[n];
            o_[j] = aa * (1.0f / (1.0f + expf(-aa))) * bb;
        }
        *(float4*)(h + (size_t)m * 512 + n0 + tx * 4) = *(float4*)o_;
    }
}

// ---------------- FFN stage 2: out = x1 + h@W3 + b3 ----------------
__global__ __launch_bounds__(256) void k_ffn2(const float* __restrict__ h,
                                              const float* __restrict__ W3, const float* __restrict__ b3,
                                              const float* __restrict__ x1,
                                              float* __restrict__ out) {
    constexpr int BM = 128, BN = 128, BK = 32;
    __shared__ float As[BK][BM + 4];
    __shared__ float Bs[BK][BN + 4];
    int m0 = blockIdx.x * BM;
    int tid = threadIdx.x;
    int tx = tid & 15, ty = tid >> 4;
    float acc[8][8] = {};
    for (int t = 0; t < 16; ++t) {  // K = 512
        int k0 = t * BK;
        __syncthreads();
#pragma unroll
        for (int r = 0; r < 4; ++r) {
            int idx = tid + r * 256;
            int row = idx >> 3, cv = idx & 7;
            float4 v = *(const float4*)(h + (size_t)(m0 + row) * 512 + k0 + cv * 4);
            As[cv * 4 + 0][row] = v.x; As[cv * 4 + 1][row] = v.y;
            As[cv * 4 + 2][row] = v.z; As[cv * 4 + 3][row] = v.w;
        }
#pragma unroll
        for (int r = 0; r < 4; ++r) {
            int idx = tid + r * 256;
            int row = idx >> 5, cv = idx & 31;
            *(float4*)&Bs[row][cv * 4] = *(const float4*)(W3 + (size_t)(k0 + row) * 128 + cv * 4);
        }
        __syncthreads();
#pragma unroll
        for (int kk = 0; kk < BK; ++kk) {
            float a_[8], b_[8];
#pragma unroll
            for (int i = 0; i < 8; ++i) a_[i] = As[kk][ty * 8 + i];
#pragma unroll
            for (int j = 0; j < 8; ++j) b_[j] = Bs[kk][tx * 8 + j];
#pragma unroll
            for (int i = 0; i < 8; ++i)
#pragma unroll
                for (int j = 0; j < 8; ++j) acc[i][j] += a_[i] * b_[j];
        }
    }
#pragma unroll
    for (int i = 0; i < 8; ++i) {
        int m = m0 + ty * 8 + i;
        const float* xr = x1 + (size_t)m * 128;
#pragma unroll
        for (int j = 0; j < 8; j += 4) {
            int n = tx * 8 + j;
            float4 xv = *(const float4*)(xr + n);
            float4 v = {acc[i][j] + xv.x + b3[n], acc[i][j + 1] + xv.y + b3[n + 1],
                        acc[i][j + 2] + xv.z + b3[n + 2], acc[i][j + 3] + xv.w + b3[n + 3]};
            *(float4*)(out + (size_t)m * 128 + n) = v;
        }
    }
}

extern "C" void kernel_launch(void* const* d_in, const int* in_sizes, int n_in,
                              void* d_out, int out_size, void* d_ws, size_t ws_size,
                              hipStream_t stream) {
    const float* x      = (const float*)d_in[0];
    const float* bias   = (const float*)d_in[1];
    const float* attn_s = (const float*)d_in[2];
    const float* ffn_s  = (const float*)d_in[3];
    const float* Wr     = (const float*)d_in[4];
    const float* br     = (const float*)d_in[5];
    const float* E1     = (const float*)d_in[6];
    const float* E2     = (const float*)d_in[7];
    const float* lq1    = (const float*)d_in[8];
    const float* lk1    = (const float*)d_in[9];
    const float* lq2    = (const float*)d_in[10];
    const float* lk2    = (const float*)d_in[11];
    // d_in[12] = outer_lambda: unused (outer mixing matrix == identity for any w)
    const float* W1     = (const float*)d_in[13];
    const float* b1     = (const float*)d_in[14];
    const float* W2     = (const float*)d_in[15];
    const float* b2     = (const float*)d_in[16];
    const float* W3     = (const float*)d_in[17];
    const float* b3     = (const float*)d_in[18];

    float* ws  = (float*)d_ws;
    float* xn  = ws + OFF_XN;
    float* x1  = ws + OFF_X1;
    float* rt  = ws + OFF_RT;
    float* A1n = ws + OFF_A1;
    float* A2n = ws + OFF_A2;
    float* Y   = ws + OFF_Y;
    float* h   = ws + OFF_H;
    float* lam = ws + OFF_LAM;

    float* out_x   = (float*)d_out;
    float* out_idx = out_x + (size_t)BN_ROWS * DIM_;  // indices stored as float values

    float lam_init = 0.8f - 0.6f * expf(-0.3f);  // DEPTH = 1

    hipLaunchKernelGGL(k_lambda, dim3(1), dim3(64), 0, stream, lq1, lk1, lq2, lk2, lam_init, lam);
    hipLaunchKernelGGL(k_rmsnorm, dim3(BN_ROWS / 4), dim3(256), 0, stream, x, attn_s, xn);
    hipLaunchKernelGGL(k_route, dim3(BN_ROWS / 4), dim3(256), 0, stream, xn, Wr, br, bias, rt, out_idx);
    hipLaunchKernelGGL(k_softmax_g, dim3(2 * E_ * N_ / 8), dim3(256), 0, stream, E1, A1n);
    hipLaunchKernelGGL(k_softmax_n, dim3(2 * E_ * G_ / 4), dim3(256), 0, stream, E2, A2n);
    hipLaunchKernelGGL(k_gemm_y, dim3(4, B_ * 2), dim3(256), 0, stream, A2n, xn, Y);
    hipLaunchKernelGGL(k_attn, dim3(4, B_), dim3(256), 0, stream, A1n, rt, Y, x, lam, x1);
    hipLaunchKernelGGL(k_rmsnorm, dim3(BN_ROWS / 4), dim3(256), 0, stream, x1, ffn_s, xn);  // xn2 reuses xn
    hipLaunchKernelGGL(k_ffn1, dim3(8, 256), dim3(256), 0, stream, xn, W1, b1, W2, b2, h);
    hipLaunchKernelGGL(k_ffn2, dim3(256), dim3(256), 0, stream, h, W3, b3, x1, out_x);
}

// Round 4
// 234.353 us; speedup vs baseline: 2.6246x; 2.6246x over previous
//
#include <hip/hip_runtime.h>
#include <math.h>

#define B_ 64
#define N_ 512
#define DIM_ 128
#define E_ 16
#define G_ 32
#define TOPK_ 4
#define HID_ 512

constexpr int BN_ROWS = B_ * N_;  // 32768

using bf16x8 = __attribute__((ext_vector_type(8))) short;
using s16x4  = __attribute__((ext_vector_type(4))) short;
using f32x4  = __attribute__((ext_vector_type(4))) float;

__device__ __forceinline__ float bf2f(short s) {
    union { unsigned u; float f; } x;
    x.u = ((unsigned)(unsigned short)s) << 16;
    return x.f;
}
__device__ __forceinline__ short f2bf(float f) {
    union { float f; unsigned u; } x;
    x.f = f;
    unsigned r = x.u + 0x7FFF + ((x.u >> 16) & 1);  // RNE
    return (short)(r >> 16);
}

// read one MFMA fragment (8 bf16, 16B) from a [rows][64] bf16 LDS tile with XOR swizzle
__device__ __forceinline__ bf16x8 frag_ld(const short* base, int row, int ks, int lhi) {
    int addr = row * 128 + (((ks * 64) + lhi * 16) ^ ((row & 7) << 4));
    return *(const bf16x8*)((const char*)base + addr);
}

// ---------------- lambda_full ----------------
__global__ void k_lambda(const float* __restrict__ lq1, const float* __restrict__ lk1,
                         const float* __restrict__ lq2, const float* __restrict__ lk2,
                         float lam_init, float* __restrict__ lam_out) {
    int l = threadIdx.x;  // 64 threads
    float s1 = lq1[l] * lk1[l] + lq1[l + 64] * lk1[l + 64];
    float s2 = lq2[l] * lk2[l] + lq2[l + 64] * lk2[l + 64];
    for (int off = 32; off; off >>= 1) {
        s1 += __shfl_xor(s1, off);
        s2 += __shfl_xor(s2, off);
    }
    if (l == 0) lam_out[0] = -(expf(s1) - expf(s2) + lam_init);
}

// ---------------- rmsnorm -> f32 (for routing + transpose) ----------------
__global__ void k_rmsnorm_f32(const float* __restrict__ in, const float* __restrict__ scale,
                              float* __restrict__ out) {
    int row  = blockIdx.x * 4 + (threadIdx.x >> 6);
    int lane = threadIdx.x & 63;
    float2 v = ((const float2*)(in + (size_t)row * DIM_))[lane];
    float ss = v.x * v.x + v.y * v.y;
    for (int off = 32; off; off >>= 1) ss += __shfl_xor(ss, off);
    float inv = 1.0f / (sqrtf(ss * (1.0f / DIM_)) + 1e-8f);
    float2 s = ((const float2*)scale)[lane];
    float2 o;
    o.x = v.x * inv * s.x;
    o.y = v.y * inv * s.y;
    ((float2*)(out + (size_t)row * DIM_))[lane] = o;
}

// ---------------- rmsnorm -> bf16 row-major (ffn A operand) ----------------
__global__ void k_rmsnorm_bf16(const float* __restrict__ in, const float* __restrict__ scale,
                               short* __restrict__ out) {
    int row  = blockIdx.x * 4 + (threadIdx.x >> 6);
    int lane = threadIdx.x & 63;
    float2 v = ((const float2*)(in + (size_t)row * DIM_))[lane];
    float ss = v.x * v.x + v.y * v.y;
    for (int off = 32; off; off >>= 1) ss += __shfl_xor(ss, off);
    float inv = 1.0f / (sqrtf(ss * (1.0f / DIM_)) + 1e-8f);
    float2 s = ((const float2*)scale)[lane];
    unsigned lo = (unsigned)(unsigned short)f2bf(v.x * inv * s.x);
    unsigned hi = (unsigned)(unsigned short)f2bf(v.y * inv * s.y);
    ((unsigned*)(out + (size_t)row * DIM_))[lane] = lo | (hi << 16);
}

// ---------------- routing: logits -> sigmoid -> top-4 -> normalized dense route ----------------
__global__ void k_route(const float* __restrict__ xn, const float* __restrict__ Wr,
                        const float* __restrict__ br, const float* __restrict__ bias,
                        float* __restrict__ route, float* __restrict__ topk_out) {
    int row  = blockIdx.x * 4 + (threadIdx.x >> 6);
    int lane = threadIdx.x & 63;
    int e = lane & 15, chunk = lane >> 4;
    const float* xr = xn + (size_t)row * DIM_;
    float acc = 0.f;
#pragma unroll
    for (int j = 0; j < 32; ++j) {
        int d = chunk * 32 + j;
        acc += xr[d] * Wr[d * E_ + e];
    }
    acc += __shfl_xor(acc, 16);
    acc += __shfl_xor(acc, 32);
    float gate = 1.0f / (1.0f + expf(-(acc + br[e])));
    float g[16];
#pragma unroll
    for (int i = 0; i < 16; ++i) g[i] = __shfl(gate, i);
    float bv = bias[0];
    unsigned sel = 0;
    int idx[4];
    float ssum = 0.f;
#pragma unroll
    for (int t = 0; t < 4; ++t) {
        float best = -1e30f;
        int bi = 0;
        float bg = 0.f;
#pragma unroll
        for (int i = 0; i < 16; ++i) {
            if (!((sel >> i) & 1)) {
                float cv = g[i] + bv;
                if (cv > best) { best = cv; bi = i; bg = g[i]; }  // strict >: lower index wins ties
            }
        }
        sel |= 1u << bi;
        idx[t] = bi;
        ssum += bg;
    }
    float inv = 1.0f / ssum;
    if (lane < 16) {
        route[(size_t)row * E_ + e] = ((sel >> e) & 1) ? gate * inv : 0.0f;
    }
    if (lane < 4) topk_out[(size_t)row * TOPK_ + lane] = (float)idx[lane];
}

// ---------------- softmax over G=32 -> bf16 ----------------
__global__ void k_softmax_g(const float* __restrict__ E1, short* __restrict__ A1nb) {
    int row = blockIdx.x * 8 + (threadIdx.x >> 5);  // 32*512 rows
    int l   = threadIdx.x & 31;
    float v = E1[(size_t)row * 32 + l];
    float m = v;
    for (int off = 16; off; off >>= 1) m = fmaxf(m, __shfl_xor(m, off));
    float ev = expf(v - m);
    float s = ev;
    for (int off = 16; off; off >>= 1) s += __shfl_xor(s, off);
    A1nb[(size_t)row * 32 + l] = f2bf(ev / s);
}

// ---------------- softmax over N=512 -> bf16 ----------------
__global__ void k_softmax_n(const float* __restrict__ E2, short* __restrict__ A2nb) {
    int row = blockIdx.x * 4 + (threadIdx.x >> 6);  // 1024 rows
    int l   = threadIdx.x & 63;
    const float* p = E2 + (size_t)row * 512;
    float v[8];
    float m = -1e30f;
#pragma unroll
    for (int j = 0; j < 8; ++j) { v[j] = p[l + j * 64]; m = fmaxf(m, v[j]); }
    for (int off = 32; off; off >>= 1) m = fmaxf(m, __shfl_xor(m, off));
    float s = 0.f;
#pragma unroll
    for (int j = 0; j < 8; ++j) { v[j] = expf(v[j] - m); s += v[j]; }
    for (int off = 32; off; off >>= 1) s += __shfl_xor(s, off);
    float inv = 1.0f / s;
    short* q = A2nb + (size_t)row * 512;
#pragma unroll
    for (int j = 0; j < 8; ++j) q[l + j * 64] = f2bf(v[j] * inv);
}

// ---------------- transpose xn [b][512][128] f32 -> xnT [b][128][512] bf16 ----------------
__global__ void k_transpose_xn(const float* __restrict__ xn, short* __restrict__ xnT) {
    __shared__ float t[32][33];
    int b = blockIdx.z;
    int j0 = blockIdx.x * 32, c0 = blockIdx.y * 32;
    int tx = threadIdx.x, ty = threadIdx.y;  // (32, 8)
    const float* src = xn + ((size_t)b * 512 + j0) * 128 + c0;
#pragma unroll
    for (int r = 0; r < 4; ++r) t[ty * 4 + r][tx] = src[(size_t)(ty * 4 + r) * 128 + tx];
    __syncthreads();
    short* dst = xnT + ((size_t)b * 128 + c0) * 512 + j0;
#pragma unroll
    for (int r = 0; r < 4; ++r) dst[(size_t)(ty * 4 + r) * 512 + tx] = f2bf(t[tx][ty * 4 + r]);
}

// ---------------- transpose W1/W2 ([128][512]) and W3 ([512][128]) -> bf16 [C][R] ----------------
__global__ void k_transpose_w(const float* __restrict__ W1, const float* __restrict__ W2,
                              const float* __restrict__ W3, short* __restrict__ W1T,
                              short* __restrict__ W2T, short* __restrict__ W3T) {
    __shared__ float t[32][33];
    int m = blockIdx.y;
    const float* S = (m == 0) ? W1 : (m == 1) ? W2 : W3;
    short* D = (m == 0) ? W1T : (m == 1) ? W2T : W3T;
    int R = (m == 2) ? 512 : 128, C = (m == 2) ? 128 : 512;
    int ctiles = C / 32;
    int r0 = (blockIdx.x / ctiles) * 32, c0 = (blockIdx.x % ctiles) * 32;
    int tx = threadIdx.x, ty = threadIdx.y;
#pragma unroll
    for (int r = 0; r < 4; ++r) t[ty * 4 + r][tx] = S[(size_t)(r0 + ty * 4 + r) * C + c0 + tx];
    __syncthreads();
#pragma unroll
    for (int r = 0; r < 4; ++r) D[(size_t)(c0 + ty * 4 + r) * R + r0 + tx] = f2bf(t[tx][ty * 4 + r]);
}

// ---------------- Y-GEMM (MFMA): YT[b][c][e*512+kd] = sum_j A2nb[e][kd][j] * xnT[b][c][j] ----------------
// BM=128 (kd), BN=128 (c), BK=64, 256 thr = 4 waves (2x2), frag grid 4x4 per wave.
__global__ __launch_bounds__(256) void k_gemm_y(const short* __restrict__ A2nb,
                                                const short* __restrict__ xnT,
                                                short* __restrict__ YT) {
    __shared__ short As[128 * 64];
    __shared__ short Bs[128 * 64];
    int be = blockIdx.y, b = be >> 1, e = be & 1;
    int m0 = blockIdx.x * 128;
    int tid = threadIdx.x, lane = tid & 63, wid = tid >> 6;
    int l15 = lane & 15, lhi = lane >> 4;
    int wr = wid >> 1, wc = wid & 1;
    const short* Asrc = A2nb + (size_t)e * 512 * 512 + (size_t)m0 * 512;
    const short* Bsrc = xnT + (size_t)b * 128 * 512;
    f32x4 acc[4][4] = {};
    for (int step = 0; step < 8; ++step) {
        int k0 = step * 64;
        __syncthreads();
#pragma unroll
        for (int r = 0; r < 4; ++r) {
            int idx = tid + r * 256;
            int row = idx >> 3, slot = idx & 7;
            bf16x8 v = *(const bf16x8*)(Asrc + (size_t)row * 512 + k0 + slot * 8);
            *(bf16x8*)((char*)As + row * 128 + ((slot * 16) ^ ((row & 7) << 4))) = v;
        }
#pragma unroll
        for (int r = 0; r < 4; ++r) {
            int idx = tid + r * 256;
            int row = idx >> 3, slot = idx & 7;
            bf16x8 v = *(const bf16x8*)(Bsrc + (size_t)row * 512 + k0 + slot * 8);
            *(bf16x8*)((char*)Bs + row * 128 + ((slot * 16) ^ ((row & 7) << 4))) = v;
        }
        __syncthreads();
#pragma unroll
        for (int ks = 0; ks < 2; ++ks) {
            bf16x8 af[4], bfr[4];
#pragma unroll
            for (int i = 0; i < 4; ++i) af[i] = frag_ld(As, wr * 64 + i * 16 + l15, ks, lhi);
#pragma unroll
            for (int j = 0; j < 4; ++j) bfr[j] = frag_ld(Bs, wc * 64 + j * 16 + l15, ks, lhi);
#pragma unroll
            for (int i = 0; i < 4; ++i)
#pragma unroll
                for (int j = 0; j < 4; ++j)
                    acc[i][j] = __builtin_amdgcn_mfma_f32_16x16x32_bf16(af[i], bfr[j], acc[i][j], 0, 0, 0);
        }
    }
    short* Yb = YT + (size_t)b * 128 * 1024 + e * 512;
#pragma unroll
    for (int i = 0; i < 4; ++i) {
        int mbase = m0 + wr * 64 + i * 16 + lhi * 4;
#pragma unroll
        for (int j = 0; j < 4; ++j) {
            int n = wc * 64 + j * 16 + l15;  // c
            s16x4 o;
#pragma unroll
            for (int q = 0; q < 4; ++q) o[q] = f2bf(acc[i][j][q]);
            *(s16x4*)(Yb + (size_t)n * 1024 + mbase) = o;
        }
    }
}

// ---------------- attn (MFMA): x1[b][i][c] = x + sum_k (route*lam*A1n)[i][k] * YT[b][c][k] ----------------
// BM=64 (i), BN=128 (c), K=1024 (16 steps of 64 = 2 t-chunks). Waves 2x2, frags 2x4.
__global__ __launch_bounds__(256) void k_attn(const short* __restrict__ A1nb,   // [32][512][32]
                                              const float* __restrict__ route,  // [B*N][16]
                                              const short* __restrict__ YT,     // [b][128][1024]
                                              const float* __restrict__ x,
                                              const float* __restrict__ lam_p,
                                              float* __restrict__ x1) {
    __shared__ short As[64 * 64];
    __shared__ short Bs[128 * 64];
    int b = blockIdx.y;
    int m0 = blockIdx.x * 64;
    float lam = lam_p[0];
    int tid = threadIdx.x, lane = tid & 63, wid = tid >> 6;
    int l15 = lane & 15, lhi = lane >> 4;
    int wr = wid >> 1, wc = wid & 1;
    f32x4 acc[2][4] = {};
    for (int step = 0; step < 16; ++step) {
        __syncthreads();
#pragma unroll
        for (int r = 0; r < 2; ++r) {  // A stage: scaled A1n, 64 rows x 8 slots
            int idx = tid + r * 256;
            int row = idx >> 3, slot = idx & 7;
            int t = step * 2 + (slot >> 2);
            int gi = m0 + row;
            float rw = route[((size_t)b * 512 + gi) * 16 + (t & 15)] * (t >= 16 ? lam : 1.0f);
            bf16x8 v = *(const bf16x8*)(A1nb + ((size_t)t * 512 + gi) * 32 + (slot & 3) * 8);
            bf16x8 o;
#pragma unroll
            for (int q = 0; q < 8; ++q) o[q] = f2bf(bf2f(v[q]) * rw);
            *(bf16x8*)((char*)As + row * 128 + ((slot * 16) ^ ((row & 7) << 4))) = o;
        }
#pragma unroll
        for (int r = 0; r < 4; ++r) {  // B stage: YT rows (c), 128 x 8 slots
            int idx = tid + r * 256;
            int row = idx >> 3, slot = idx & 7;
            bf16x8 v = *(const bf16x8*)(YT + ((size_t)b * 128 + row) * 1024 + step * 64 + slot * 8);
            *(bf16x8*)((char*)Bs + row * 128 + ((slot * 16) ^ ((row & 7) << 4))) = v;
        }
        __syncthreads();
#pragma unroll
        for (int ks = 0; ks < 2; ++ks) {
            bf16x8 af[2], bfr[4];
#pragma unroll
            for (int i = 0; i < 2; ++i) af[i] = frag_ld(As, wr * 32 + i * 16 + l15, ks, lhi);
#pragma unroll
            for (int j = 0; j < 4; ++j) bfr[j] = frag_ld(Bs, wc * 64 + j * 16 + l15, ks, lhi);
#pragma unroll
            for (int i = 0; i < 2; ++i)
#pragma unroll
                for (int j = 0; j < 4; ++j)
                    acc[i][j] = __builtin_amdgcn_mfma_f32_16x16x32_bf16(af[i], bfr[j], acc[i][j], 0, 0, 0);
        }
    }
#pragma unroll
    for (int i = 0; i < 2; ++i) {
        int gibase = m0 + wr * 32 + i * 16 + lhi * 4;
#pragma unroll
        for (int j = 0; j < 4; ++j) {
            int n = wc * 64 + j * 16 + l15;
#pragma unroll
            for (int q = 0; q < 4; ++q) {
                size_t off = ((size_t)b * 512 + gibase + q) * 128 + n;
                x1[off] = acc[i][j][q] + x[off];
            }
        }
    }
}

// ---------------- FFN1 (MFMA, fused W1/W2 + SwiGLU): h[m][n] bf16 ----------------
// BM=128, BN=64 per weight, BK=64, K=128 (2 steps). Waves 2x2, frags 4x2 per weight.
__global__ __launch_bounds__(256) void k_ffn1(const short* __restrict__ xn2b,
                                              const short* __restrict__ W1T, const float* __restrict__ b1,
                                              const short* __restrict__ W2T, const float* __restrict__ b2,
                                              short* __restrict__ h) {
    __shared__ short As[128 * 64];
    __shared__ short B1s[64 * 64];
    __shared__ short B2s[64 * 64];
    int m0 = blockIdx.x * 128, n0 = blockIdx.y * 64;
    int tid = threadIdx.x, lane = tid & 63, wid = tid >> 6;
    int l15 = lane & 15, lhi = lane >> 4;
    int wr = wid >> 1, wc = wid & 1;
    f32x4 acc1[4][2] = {}, acc2[4][2] = {};
    for (int step = 0; step < 2; ++step) {
        int k0 = step * 64;
        __syncthreads();
#pragma unroll
        for (int r = 0; r < 4; ++r) {
            int idx = tid + r * 256;
            int row = idx >> 3, slot = idx & 7;
            bf16x8 v = *(const bf16x8*)(xn2b + (size_t)(m0 + row) * 128 + k0 + slot * 8);
            *(bf16x8*)((char*)As + row * 128 + ((slot * 16) ^ ((row & 7) << 4))) = v;
        }
#pragma unroll
        for (int r = 0; r < 4; ++r) {
            int idx = tid + r * 256;  // 0..1023: first 512 -> B1, rest -> B2
            int which = idx >> 9;
            int row = (idx >> 3) & 63, slot = idx & 7;
            const short* S = which ? W2T : W1T;
            short* D = which ? (short*)B2s : (short*)B1s;
            bf16x8 v = *(const bf16x8*)(S + (size_t)(n0 + row) * 128 + k0 + slot * 8);
            *(bf16x8*)((char*)D + row * 128 + ((slot * 16) ^ ((row & 7) << 4))) = v;
        }
        __syncthreads();
#pragma unroll
        for (int ks = 0; ks < 2; ++ks) {
            bf16x8 af[4], b1f[2], b2f[2];
#pragma unroll
            for (int i = 0; i < 4; ++i) af[i] = frag_ld(As, wr * 64 + i * 16 + l15, ks, lhi);
#pragma unroll
            for (int j = 0; j < 2; ++j) {
                b1f[j] = frag_ld(B1s, wc * 32 + j * 16 + l15, ks, lhi);
                b2f[j] = frag_ld(B2s, wc * 32 + j * 16 + l15, ks, lhi);
            }
#pragma unroll
            for (int i = 0; i < 4; ++i)
#pragma unroll
                for (int j = 0; j < 2; ++j) {
                    acc1[i][j] = __builtin_amdgcn_mfma_f32_16x16x32_bf16(af[i], b1f[j], acc1[i][j], 0, 0, 0);
                    acc2[i][j] = __builtin_amdgcn_mfma_f32_16x16x32_bf16(af[i], b2f[j], acc2[i][j], 0, 0, 0);
                }
        }
    }
    // epilogue: SwiGLU -> bf16 h-tile in LDS (reuse As) -> coalesced store
    __syncthreads();
#pragma unroll
    for (int i = 0; i < 4; ++i) {
        int mloc = wr * 64 + i * 16 + lhi * 4;
#pragma unroll
        for (int j = 0; j < 2; ++j) {
            int nloc = wc * 32 + j * 16 + l15;
            int n = n0 + nloc;
            float bb1 = b1[n], bb2 = b2[n];
#pragma unroll
            for (int q = 0; q < 4; ++q) {
                float a1 = acc1[i][j][q] + bb1;
                float a2 = acc2[i][j][q] + bb2;
                float hv = a1 / (1.0f + expf(-a1)) * a2;
                ((short*)As)[(mloc + q) * 64 + nloc] = f2bf(hv);
            }
        }
    }
    __syncthreads();
#pragma unroll
    for (int r = 0; r < 4; ++r) {
        int idx = tid + r * 256;
        int row = idx >> 3, slot = idx & 7;
        *(bf16x8*)(h + (size_t)(m0 + row) * 512 + n0 + slot * 8) =
            *(const bf16x8*)((char*)As + row * 128 + slot * 16);
    }
}

// ---------------- FFN2 (MFMA): out = x1 + h @ W3 + b3 ----------------
// BM=64, BN=128, K=512 (8 steps). Waves 2x2, frags 2x4.
__global__ __launch_bounds__(256) void k_ffn2(const short* __restrict__ h,
                                              const short* __restrict__ W3T, const float* __restrict__ b3,
                                              const float* __restrict__ x1,
                                              float* __restrict__ out) {
    __shared__ short As[64 * 64];
    __shared__ short Bs[128 * 64];
    int m0 = blockIdx.x * 64;
    int tid = threadIdx.x, lane = tid & 63, wid = tid >> 6;
    int l15 = lane & 15, lhi = lane >> 4;
    int wr = wid >> 1, wc = wid & 1;
    f32x4 acc[2][4] = {};
    for (int step = 0; step < 8; ++step) {
        int k0 = step * 64;
        __syncthreads();
#pragma unroll
        for (int r = 0; r < 2; ++r) {
            int idx = tid + r * 256;
            int row = idx >> 3, slot = idx & 7;
            bf16x8 v = *(const bf16x8*)(h + (size_t)(m0 + row) * 512 + k0 + slot * 8);
            *(bf16x8*)((char*)As + row * 128 + ((slot * 16) ^ ((row & 7) << 4))) = v;
        }
#pragma unroll
        for (int r = 0; r < 4; ++r) {
            int idx = tid + r * 256;
            int row = idx >> 3, slot = idx & 7;
            bf16x8 v = *(const bf16x8*)(W3T + (size_t)row * 512 + k0 + slot * 8);
            *(bf16x8*)((char*)Bs + row * 128 + ((slot * 16) ^ ((row & 7) << 4))) = v;
        }
        __syncthreads();
#pragma unroll
        for (int ks = 0; ks < 2; ++ks) {
            bf16x8 af[2], bfr[4];
#pragma unroll
            for (int i = 0; i < 2; ++i) af[i] = frag_ld(As, wr * 32 + i * 16 + l15, ks, lhi);
#pragma unroll
            for (int j = 0; j < 4; ++j) bfr[j] = frag_ld(Bs, wc * 64 + j * 16 + l15, ks, lhi);
#pragma unroll
            for (int i = 0; i < 2; ++i)
#pragma unroll
                for (int j = 0; j < 4; ++j)
                    acc[i][j] = __builtin_amdgcn_mfma_f32_16x16x32_bf16(af[i], bfr[j], acc[i][j], 0, 0, 0);
        }
    }
#pragma unroll
    for (int i = 0; i < 2; ++i) {
        int mbase = m0 + wr * 32 + i * 16 + lhi * 4;
#pragma unroll
        for (int j = 0; j < 4; ++j) {
            int n = wc * 64 + j * 16 + l15;
            float bv = b3[n];
#pragma unroll
            for (int q = 0; q < 4; ++q) {
                size_t off = (size_t)(mbase + q) * 128 + n;
                out[off] = acc[i][j][q] + x1[off] + bv;
            }
        }
    }
}

// ---- workspace layout (bytes) ----
constexpr size_t ALIGN_UP(size_t x) { return (x + 255) & ~(size_t)255; }
constexpr size_t SZ_XN   = ALIGN_UP((size_t)BN_ROWS * DIM_ * 4);       // f32
constexpr size_t SZ_X1   = ALIGN_UP((size_t)BN_ROWS * DIM_ * 4);       // f32
constexpr size_t SZ_RT   = ALIGN_UP((size_t)BN_ROWS * E_ * 4);         // f32
constexpr size_t SZ_A1   = ALIGN_UP((size_t)32 * 512 * 32 * 2);        // bf16
constexpr size_t SZ_A2   = ALIGN_UP((size_t)2 * 512 * 512 * 2);        // bf16
constexpr size_t SZ_XNT  = ALIGN_UP((size_t)B_ * 128 * 512 * 2);       // bf16
constexpr size_t SZ_YT   = ALIGN_UP((size_t)B_ * 128 * 1024 * 2);      // bf16
constexpr size_t SZ_XN2B = ALIGN_UP((size_t)BN_ROWS * DIM_ * 2);       // bf16
constexpr size_t SZ_H    = ALIGN_UP((size_t)BN_ROWS * HID_ * 2);       // bf16
constexpr size_t SZ_WT   = ALIGN_UP((size_t)128 * 512 * 2);            // bf16 (each)

extern "C" void kernel_launch(void* const* d_in, const int* in_sizes, int n_in,
                              void* d_out, int out_size, void* d_ws, size_t ws_size,
                              hipStream_t stream) {
    const float* x      = (const float*)d_in[0];
    const float* bias   = (const float*)d_in[1];
    const float* attn_s = (const float*)d_in[2];
    const float* ffn_s  = (const float*)d_in[3];
    const float* Wr     = (const float*)d_in[4];
    const float* br     = (const float*)d_in[5];
    const float* E1     = (const float*)d_in[6];
    const float* E2     = (const float*)d_in[7];
    const float* lq1    = (const float*)d_in[8];
    const float* lk1    = (const float*)d_in[9];
    const float* lq2    = (const float*)d_in[10];
    const float* lk2    = (const float*)d_in[11];
    // d_in[12] = outer_lambda: unused (outer mixing matrix == identity)
    const float* W1     = (const float*)d_in[13];
    const float* b1     = (const float*)d_in[14];
    const float* W2     = (const float*)d_in[15];
    const float* b2     = (const float*)d_in[16];
    const float* W3     = (const float*)d_in[17];
    const float* b3     = (const float*)d_in[18];

    char* p = (char*)d_ws;
    float* xn   = (float*)p;            p += SZ_XN;
    float* x1   = (float*)p;            p += SZ_X1;
    float* rt   = (float*)p;            p += SZ_RT;
    short* A1nb = (short*)p;            p += SZ_A1;
    short* A2nb = (short*)p;            p += SZ_A2;
    short* xnT  = (short*)p;            p += SZ_XNT;
    short* YT   = (short*)p;            p += SZ_YT;
    short* xn2b = (short*)p;            p += SZ_XN2B;
    short* h    = (short*)p;            p += SZ_H;
    short* W1T  = (short*)p;            p += SZ_WT;
    short* W2T  = (short*)p;            p += SZ_WT;
    short* W3T  = (short*)p;            p += SZ_WT;
    float* lam  = (float*)p;            p += 256;

    float* out_x   = (float*)d_out;
    float* out_idx = out_x + (size_t)BN_ROWS * DIM_;  // indices stored as float values

    float lam_init = 0.8f - 0.6f * expf(-0.3f);  // DEPTH = 1

    hipLaunchKernelGGL(k_lambda, dim3(1), dim3(64), 0, stream, lq1, lk1, lq2, lk2, lam_init, lam);
    hipLaunchKernelGGL(k_rmsnorm_f32, dim3(BN_ROWS / 4), dim3(256), 0, stream, x, attn_s, xn);
    hipLaunchKernelGGL(k_route, dim3(BN_ROWS / 4), dim3(256), 0, stream, xn, Wr, br, bias, rt, out_idx);
    hipLaunchKernelGGL(k_transpose_xn, dim3(16, 4, 64), dim3(32, 8), 0, stream, xn, xnT);
    hipLaunchKernelGGL(k_softmax_g, dim3(32 * 512 / 8), dim3(256), 0, stream, E1, A1nb);
    hipLaunchKernelGGL(k_softmax_n, dim3(1024 / 4), dim3(256), 0, stream, E2, A2nb);
    hipLaunchKernelGGL(k_transpose_w, dim3(64, 3), dim3(32, 8), 0, stream, W1, W2, W3, W1T, W2T, W3T);
    hipLaunchKernelGGL(k_gemm_y, dim3(4, 128), dim3(256), 0, stream, A2nb, xnT, YT);
    hipLaunchKernelGGL(k_attn, dim3(8, 64), dim3(256), 0, stream, A1nb, rt, YT, x, lam, x1);
    hipLaunchKernelGGL(k_rmsnorm_bf16, dim3(BN_ROWS / 4), dim3(256), 0, stream, x1, ffn_s, xn2b);
    hipLaunchKernelGGL(k_ffn1, dim3(256, 8), dim3(256), 0, stream, xn2b, W1T, b1, W2T, b2, h);
    hipLaunchKernelGGL(k_ffn2, dim3(512), dim3(256), 0, stream, h, W3T, b3, x1, out_x);
}

// Round 5
// 212.581 us; speedup vs baseline: 2.8933x; 1.1024x over previous
//
#include <hip/hip_runtime.h>
#include <math.h>

#define B_ 64
#define N_ 512
#define DIM_ 128
#define E_ 16
#define G_ 32
#define TOPK_ 4
#define HID_ 512

constexpr int BN_ROWS = B_ * N_;  // 32768

using bf16x8 = __attribute__((ext_vector_type(8))) short;
using s16x4  = __attribute__((ext_vector_type(4))) short;
using f32x4  = __attribute__((ext_vector_type(4))) float;

__device__ __forceinline__ float bf2f(short s) {
    union { unsigned u; float f; } x;
    x.u = ((unsigned)(unsigned short)s) << 16;
    return x.f;
}
__device__ __forceinline__ short f2bf(float f) {
    union { float f; unsigned u; } x;
    x.f = f;
    unsigned r = x.u + 0x7FFF + ((x.u >> 16) & 1);  // RNE
    return (short)(r >> 16);
}

// read one MFMA fragment (8 bf16, 16B) from a [rows][64] bf16 LDS tile with XOR swizzle
__device__ __forceinline__ bf16x8 frag_ld(const short* base, int row, int ks, int lhi) {
    int addr = row * 128 + (((ks * 64) + lhi * 16) ^ ((row & 7) << 4));
    return *(const bf16x8*)((const char*)base + addr);
}

// ================= k_misc: all preprocessing in ONE launch, grid-sectioned =================
constexpr int NPRE = BN_ROWS / 4;     // 8192: fused rmsnorm+route (4 rows/block)
constexpr int NXNT = B_ * 16;         // 1024: fused rmsnorm+transpose -> xnT bf16 (32 rows/block)
constexpr int NSMG = 32 * 512 / 8;    // 2048: softmax over G
constexpr int NSMN = 1024 / 4;        // 256: softmax over N
constexpr int NTW  = 64 * 3;          // 192: weight transposes
constexpr int NMISC = NPRE + NXNT + NSMG + NSMN + NTW + 1;  // +1 lambda

__global__ __launch_bounds__(256) void k_misc(
    const float* __restrict__ x, const float* __restrict__ attn_s,
    const float* __restrict__ Wr, const float* __restrict__ br, const float* __restrict__ bias,
    float* __restrict__ route, float* __restrict__ topk_out,
    short* __restrict__ xnT,
    const float* __restrict__ E1, short* __restrict__ A1nb,
    const float* __restrict__ E2, short* __restrict__ A2nb,
    const float* __restrict__ W1, const float* __restrict__ W2, const float* __restrict__ W3,
    short* __restrict__ W1T, short* __restrict__ W2T, short* __restrict__ W3T,
    const float* __restrict__ lq1, const float* __restrict__ lk1,
    const float* __restrict__ lq2, const float* __restrict__ lk2,
    float lam_init, float* __restrict__ lam_out) {
    __shared__ float xbuf[4][132];
    __shared__ float tb[32][129];
    __shared__ float invb[32];
    __shared__ float tw[32][33];
    int blk = blockIdx.x;
    int tid = threadIdx.x;

    if (blk < NPRE) {  // ---- fused rmsnorm + route: wave = one row ----
        int w = tid >> 6, lane = tid & 63;
        int row = blk * 4 + w;
        float2 v = ((const float2*)(x + (size_t)row * DIM_))[lane];
        float ss = v.x * v.x + v.y * v.y;
        for (int off = 32; off; off >>= 1) ss += __shfl_xor(ss, off);
        float inv = 1.0f / (sqrtf(ss * (1.0f / DIM_)) + 1e-8f);
        float2 s = ((const float2*)attn_s)[lane];
        xbuf[w][lane * 2]     = v.x * inv * s.x;
        xbuf[w][lane * 2 + 1] = v.y * inv * s.y;
        // same wave produces & consumes xbuf[w] -> no barrier needed
        int e = lane & 15, chunk = lane >> 4;
        float acc = 0.f;
#pragma unroll
        for (int j = 0; j < 32; ++j) {
            int d = chunk * 32 + j;
            acc += xbuf[w][d] * Wr[d * E_ + e];
        }
        acc += __shfl_xor(acc, 16);
        acc += __shfl_xor(acc, 32);
        float gate = 1.0f / (1.0f + expf(-(acc + br[e])));
        float g[16];
#pragma unroll
        for (int i = 0; i < 16; ++i) g[i] = __shfl(gate, i);
        float bv = bias[0];
        unsigned sel = 0;
        int idx[4];
        float ssum = 0.f;
#pragma unroll
        for (int t = 0; t < 4; ++t) {
            float best = -1e30f;
            int bi = 0;
            float bg = 0.f;
#pragma unroll
            for (int i = 0; i < 16; ++i) {
                if (!((sel >> i) & 1)) {
                    float cv = g[i] + bv;
                    if (cv > best) { best = cv; bi = i; bg = g[i]; }  // strict >: lower idx wins ties
                }
            }
            sel |= 1u << bi;
            idx[t] = bi;
            ssum += bg;
        }
        float rinv = 1.0f / ssum;
        if (lane < 16) route[(size_t)row * E_ + e] = ((sel >> e) & 1) ? gate * rinv : 0.0f;
        if (lane < 4) topk_out[(size_t)row * TOPK_ + lane] = (float)idx[lane];
        return;
    }
    blk -= NPRE;

    if (blk < NXNT) {  // ---- fused rmsnorm + transpose: xnT[b][c][j] bf16 ----
        int b = blk >> 4, j0 = (blk & 15) * 32;
        const float* src = x + (size_t)(b * 512 + j0) * 128;
        int r = tid >> 3, c8 = tid & 7;
#pragma unroll
        for (int it = 0; it < 4; ++it) {
            int c4 = c8 + it * 8;
            float4 w4 = *(const float4*)(src + (size_t)r * 128 + c4 * 4);
            tb[r][c4 * 4 + 0] = w4.x; tb[r][c4 * 4 + 1] = w4.y;
            tb[r][c4 * 4 + 2] = w4.z; tb[r][c4 * 4 + 3] = w4.w;
        }
        __syncthreads();
        int sg = tid & 7;
        float ps = 0.f;
#pragma unroll
        for (int j = 0; j < 16; ++j) { float e2 = tb[r][sg * 16 + j]; ps += e2 * e2; }
        ps += __shfl_xor(ps, 1); ps += __shfl_xor(ps, 2); ps += __shfl_xor(ps, 4);
        if (sg == 0) invb[r] = 1.0f / (sqrtf(ps * (1.0f / DIM_)) + 1e-8f);
        __syncthreads();
        int c = tid >> 1, half = tid & 1;
        float sc = attn_s[c];
        short ov[16];
#pragma unroll
        for (int j = 0; j < 16; ++j) {
            int jj = half * 16 + j;
            ov[j] = f2bf(tb[jj][c] * invb[jj] * sc);
        }
        short* dst = xnT + (size_t)(b * 128 + c) * 512 + j0 + half * 16;
        *(bf16x8*)dst = *(bf16x8*)ov;
        *(bf16x8*)(dst + 8) = *(bf16x8*)(ov + 8);
        return;
    }
    blk -= NXNT;

    if (blk < NSMG) {  // ---- softmax over G=32 -> bf16 ----
        int row = blk * 8 + (tid >> 5);
        int l = tid & 31;
        float v = E1[(size_t)row * 32 + l];
        float m = v;
        for (int off = 16; off; off >>= 1) m = fmaxf(m, __shfl_xor(m, off));
        float ev = expf(v - m);
        float s = ev;
        for (int off = 16; off; off >>= 1) s += __shfl_xor(s, off);
        A1nb[(size_t)row * 32 + l] = f2bf(ev / s);
        return;
    }
    blk -= NSMG;

    if (blk < NSMN) {  // ---- softmax over N=512 -> bf16 ----
        int row = blk * 4 + (tid >> 6);
        int l = tid & 63;
        const float* p = E2 + (size_t)row * 512;
        float v[8];
        float m = -1e30f;
#pragma unroll
        for (int j = 0; j < 8; ++j) { v[j] = p[l + j * 64]; m = fmaxf(m, v[j]); }
        for (int off = 32; off; off >>= 1) m = fmaxf(m, __shfl_xor(m, off));
        float s = 0.f;
#pragma unroll
        for (int j = 0; j < 8; ++j) { v[j] = expf(v[j] - m); s += v[j]; }
        for (int off = 32; off; off >>= 1) s += __shfl_xor(s, off);
        float inv = 1.0f / s;
        short* q = A2nb + (size_t)row * 512;
#pragma unroll
        for (int j = 0; j < 8; ++j) q[l + j * 64] = f2bf(v[j] * inv);
        return;
    }
    blk -= NSMN;

    if (blk < NTW) {  // ---- weight transposes -> bf16 [C][R] ----
        int m = blk >> 6, tile = blk & 63;
        const float* S = (m == 0) ? W1 : (m == 1) ? W2 : W3;
        short* D = (m == 0) ? W1T : (m == 1) ? W2T : W3T;
        int R = (m == 2) ? 512 : 128, C = (m == 2) ? 128 : 512;
        int ctiles = C / 32;
        int r0 = (tile / ctiles) * 32, c0 = (tile % ctiles) * 32;
        int tx = tid & 31, ty = tid >> 5;
#pragma unroll
        for (int r = 0; r < 4; ++r) tw[ty * 4 + r][tx] = S[(size_t)(r0 + ty * 4 + r) * C + c0 + tx];
        __syncthreads();
#pragma unroll
        for (int r = 0; r < 4; ++r) D[(size_t)(c0 + ty * 4 + r) * R + r0 + tx] = f2bf(tw[tx][ty * 4 + r]);
        return;
    }

    // ---- lambda (1 block, wave 0) ----
    if (tid < 64) {
        int l = tid;
        float s1 = lq1[l] * lk1[l] + lq1[l + 64] * lk1[l + 64];
        float s2 = lq2[l] * lk2[l] + lq2[l + 64] * lk2[l + 64];
        for (int off = 32; off; off >>= 1) {
            s1 += __shfl_xor(s1, off);
            s2 += __shfl_xor(s2, off);
        }
        if (l == 0) lam_out[0] = -(expf(s1) - expf(s2) + lam_init);
    }
}

// ================= Y-GEMM (MFMA, reg-prefetch): YT[b][c][e*512+kd] = sum_j A2[e][kd][j]*xnT[b][c][j] =================
__global__ __launch_bounds__(256) void k_gemm_y(const short* __restrict__ A2nb,
                                                const short* __restrict__ xnT,
                                                short* __restrict__ YT) {
    __shared__ short As[128 * 64];
    __shared__ short Bs[128 * 64];
    int be = blockIdx.y, b = be >> 1, e = be & 1;
    int m0 = blockIdx.x * 128;
    int tid = threadIdx.x, lane = tid & 63, wid = tid >> 6;
    int l15 = lane & 15, lhi = lane >> 4;
    int wr = wid >> 1, wc = wid & 1;
    const short* Asrc = A2nb + (size_t)e * 512 * 512 + (size_t)m0 * 512;
    const short* Bsrc = xnT + (size_t)b * 128 * 512;
    bf16x8 av[4], bv[4];
#pragma unroll
    for (int r = 0; r < 4; ++r) {
        int idx = tid + r * 256, row = idx >> 3, slot = idx & 7;
        av[r] = *(const bf16x8*)(Asrc + (size_t)row * 512 + slot * 8);
        bv[r] = *(const bf16x8*)(Bsrc + (size_t)row * 512 + slot * 8);
    }
    f32x4 acc[4][4] = {};
    for (int step = 0; step < 8; ++step) {
        __syncthreads();
#pragma unroll
        for (int r = 0; r < 4; ++r) {
            int idx = tid + r * 256, row = idx >> 3, slot = idx & 7;
            *(bf16x8*)((char*)As + row * 128 + ((slot * 16) ^ ((row & 7) << 4))) = av[r];
            *(bf16x8*)((char*)Bs + row * 128 + ((slot * 16) ^ ((row & 7) << 4))) = bv[r];
        }
        __syncthreads();
        if (step < 7) {
            int k0 = (step + 1) * 64;
#pragma unroll
            for (int r = 0; r < 4; ++r) {
                int idx = tid + r * 256, row = idx >> 3, slot = idx & 7;
                av[r] = *(const bf16x8*)(Asrc + (size_t)row * 512 + k0 + slot * 8);
                bv[r] = *(const bf16x8*)(Bsrc + (size_t)row * 512 + k0 + slot * 8);
            }
        }
#pragma unroll
        for (int ks = 0; ks < 2; ++ks) {
            bf16x8 af[4], bfr[4];
#pragma unroll
            for (int i = 0; i < 4; ++i) af[i] = frag_ld(As, wr * 64 + i * 16 + l15, ks, lhi);
#pragma unroll
            for (int j = 0; j < 4; ++j) bfr[j] = frag_ld(Bs, wc * 64 + j * 16 + l15, ks, lhi);
#pragma unroll
            for (int i = 0; i < 4; ++i)
#pragma unroll
                for (int j = 0; j < 4; ++j)
                    acc[i][j] = __builtin_amdgcn_mfma_f32_16x16x32_bf16(af[i], bfr[j], acc[i][j], 0, 0, 0);
        }
    }
    short* Yb = YT + (size_t)b * 128 * 1024 + e * 512;
#pragma unroll
    for (int i = 0; i < 4; ++i) {
        int mbase = m0 + wr * 64 + i * 16 + lhi * 4;
#pragma unroll
        for (int j = 0; j < 4; ++j) {
            int n = wc * 64 + j * 16 + l15;
            s16x4 o;
#pragma unroll
            for (int q = 0; q < 4; ++q) o[q] = f2bf(acc[i][j][q]);
            *(s16x4*)(Yb + (size_t)n * 1024 + mbase) = o;
        }
    }
}

// ================= attn (MFMA, reg-prefetch, fused residual + FFN rmsnorm) =================
// x1 = x + attn; xn2b = rmsnorm(x1)*ffn_scale (block covers full DIM=128 cols -> rows complete)
__global__ __launch_bounds__(256) void k_attn(const short* __restrict__ A1nb,
                                              const float* __restrict__ route,
                                              const short* __restrict__ YT,
                                              const float* __restrict__ x,
                                              const float* __restrict__ lam_p,
                                              const float* __restrict__ ffn_s,
                                              float* __restrict__ x1,
                                              short* __restrict__ xn2b) {
    __shared__ short As[64 * 64];
    __shared__ short Bs[128 * 64];
    __shared__ float ssbuf[2][64];
    int b = blockIdx.y;
    int m0 = blockIdx.x * 64;
    float lam = lam_p[0];
    int tid = threadIdx.x, lane = tid & 63, wid = tid >> 6;
    int l15 = lane & 15, lhi = lane >> 4;
    int wr = wid >> 1, wc = wid & 1;
    float rv[2];
    bf16x8 araw[2], yv[4];
#pragma unroll
    for (int r = 0; r < 2; ++r) {
        int idx = tid + r * 256, row = idx >> 3, slot = idx & 7;
        int t = (slot >> 2);
        int gi = m0 + row;
        rv[r] = route[((size_t)b * 512 + gi) * 16 + (t & 15)];  // t<16 at step 0
        araw[r] = *(const bf16x8*)(A1nb + ((size_t)t * 512 + gi) * 32 + (slot & 3) * 8);
    }
#pragma unroll
    for (int r = 0; r < 4; ++r) {
        int idx = tid + r * 256, row = idx >> 3, slot = idx & 7;
        yv[r] = *(const bf16x8*)(YT + ((size_t)b * 128 + row) * 1024 + slot * 8);
    }
    f32x4 acc[2][4] = {};
    for (int step = 0; step < 16; ++step) {
        __syncthreads();
#pragma unroll
        for (int r = 0; r < 2; ++r) {
            int idx = tid + r * 256, row = idx >> 3, slot = idx & 7;
            bf16x8 o;
#pragma unroll
            for (int q = 0; q < 8; ++q) o[q] = f2bf(bf2f(araw[r][q]) * rv[r]);
            *(bf16x8*)((char*)As + row * 128 + ((slot * 16) ^ ((row & 7) << 4))) = o;
        }
#pragma unroll
        for (int r = 0; r < 4; ++r) {
            int idx = tid + r * 256, row = idx >> 3, slot = idx & 7;
            *(bf16x8*)((char*)Bs + row * 128 + ((slot * 16) ^ ((row & 7) << 4))) = yv[r];
        }
        __syncthreads();
        if (step < 15) {
            int sn = step + 1;
#pragma unroll
            for (int r = 0; r < 2; ++r) {
                int idx = tid + r * 256, row = idx >> 3, slot = idx & 7;
                int t = sn * 2 + (slot >> 2);
                int gi = m0 + row;
                rv[r] = route[((size_t)b * 512 + gi) * 16 + (t & 15)] * (t >= 16 ? lam : 1.0f);
                araw[r] = *(const bf16x8*)(A1nb + ((size_t)t * 512 + gi) * 32 + (slot & 3) * 8);
            }
#pragma unroll
            for (int r = 0; r < 4; ++r) {
                int idx = tid + r * 256, row = idx >> 3, slot = idx & 7;
                yv[r] = *(const bf16x8*)(YT + ((size_t)b * 128 + row) * 1024 + sn * 64 + slot * 8);
            }
        }
#pragma unroll
        for (int ks = 0; ks < 2; ++ks) {
            bf16x8 af[2], bfr[4];
#pragma unroll
            for (int i = 0; i < 2; ++i) af[i] = frag_ld(As, wr * 32 + i * 16 + l15, ks, lhi);
#pragma unroll
            for (int j = 0; j < 4; ++j) bfr[j] = frag_ld(Bs, wc * 64 + j * 16 + l15, ks, lhi);
#pragma unroll
            for (int i = 0; i < 2; ++i)
#pragma unroll
                for (int j = 0; j < 4; ++j)
                    acc[i][j] = __builtin_amdgcn_mfma_f32_16x16x32_bf16(af[i], bfr[j], acc[i][j], 0, 0, 0);
        }
    }
    // epilogue: residual, write x1, fused rmsnorm -> xn2b
    float x1v[2][4][4];
    float pss[2][4] = {};
#pragma unroll
    for (int i = 0; i < 2; ++i) {
        int gibase = m0 + wr * 32 + i * 16 + lhi * 4;
#pragma unroll
        for (int j = 0; j < 4; ++j) {
            int n = wc * 64 + j * 16 + l15;
#pragma unroll
            for (int q = 0; q < 4; ++q) {
                size_t off = ((size_t)b * 512 + gibase + q) * 128 + n;
                float val = acc[i][j][q] + x[off];
                x1[off] = val;
                x1v[i][j][q] = val;
                pss[i][q] += val * val;
            }
        }
    }
#pragma unroll
    for (int i = 0; i < 2; ++i)
#pragma unroll
        for (int q = 0; q < 4; ++q) {
            float p = pss[i][q];
            p += __shfl_xor(p, 1); p += __shfl_xor(p, 2);
            p += __shfl_xor(p, 4); p += __shfl_xor(p, 8);
            pss[i][q] = p;
        }
    if (l15 == 0) {
#pragma unroll
        for (int i = 0; i < 2; ++i)
#pragma unroll
            for (int q = 0; q < 4; ++q)
                ssbuf[wc][wr * 32 + i * 16 + lhi * 4 + q] = pss[i][q];
    }
    __syncthreads();
#pragma unroll
    for (int i = 0; i < 2; ++i)
#pragma unroll
        for (int q = 0; q < 4; ++q) {
            int rowl = wr * 32 + i * 16 + lhi * 4 + q;
            float ssum = ssbuf[0][rowl] + ssbuf[1][rowl];
            float inv = 1.0f / (sqrtf(ssum * (1.0f / DIM_)) + 1e-8f);
#pragma unroll
            for (int j = 0; j < 4; ++j) {
                int n = wc * 64 + j * 16 + l15;
                xn2b[((size_t)b * 512 + m0 + rowl) * 128 + n] = f2bf(x1v[i][j][q] * inv * ffn_s[n]);
            }
        }
}

// ================= FFN1 (MFMA, reg-prefetch, fused SwiGLU) =================
__global__ __launch_bounds__(256) void k_ffn1(const short* __restrict__ xn2b,
                                              const short* __restrict__ W1T, const float* __restrict__ b1,
                                              const short* __restrict__ W2T, const float* __restrict__ b2,
                                              short* __restrict__ h) {
    __shared__ short As[128 * 64];
    __shared__ short B1s[64 * 64];
    __shared__ short B2s[64 * 64];
    int m0 = blockIdx.x * 128, n0 = blockIdx.y * 64;
    int tid = threadIdx.x, lane = tid & 63, wid = tid >> 6;
    int l15 = lane & 15, lhi = lane >> 4;
    int wr = wid >> 1, wc = wid & 1;
    bf16x8 av[4], wv[4];
#pragma unroll
    for (int r = 0; r < 4; ++r) {
        int idx = tid + r * 256, row = idx >> 3, slot = idx & 7;
        av[r] = *(const bf16x8*)(xn2b + (size_t)(m0 + row) * 128 + slot * 8);
        int which = idx >> 9, brow = (idx >> 3) & 63;
        const short* S = which ? W2T : W1T;
        wv[r] = *(const bf16x8*)(S + (size_t)(n0 + brow) * 128 + slot * 8);
    }
    f32x4 acc1[4][2] = {}, acc2[4][2] = {};
    for (int step = 0; step < 2; ++step) {
        __syncthreads();
#pragma unroll
        for (int r = 0; r < 4; ++r) {
            int idx = tid + r * 256, row = idx >> 3, slot = idx & 7;
            *(bf16x8*)((char*)As + row * 128 + ((slot * 16) ^ ((row & 7) << 4))) = av[r];
            int which = idx >> 9, brow = (idx >> 3) & 63;
            short* D = which ? (short*)B2s : (short*)B1s;
            *(bf16x8*)((char*)D + brow * 128 + ((slot * 16) ^ ((brow & 7) << 4))) = wv[r];
        }
        __syncthreads();
        if (step == 0) {
#pragma unroll
            for (int r = 0; r < 4; ++r) {
                int idx = tid + r * 256, row = idx >> 3, slot = idx & 7;
                av[r] = *(const bf16x8*)(xn2b + (size_t)(m0 + row) * 128 + 64 + slot * 8);
                int which = idx >> 9, brow = (idx >> 3) & 63;
                const short* S = which ? W2T : W1T;
                wv[r] = *(const bf16x8*)(S + (size_t)(n0 + brow) * 128 + 64 + slot * 8);
            }
        }
#pragma unroll
        for (int ks = 0; ks < 2; ++ks) {
            bf16x8 af[4], b1f[2], b2f[2];
#pragma unroll
            for (int i = 0; i < 4; ++i) af[i] = frag_ld(As, wr * 64 + i * 16 + l15, ks, lhi);
#pragma unroll
            for (int j = 0; j < 2; ++j) {
                b1f[j] = frag_ld(B1s, wc * 32 + j * 16 + l15, ks, lhi);
                b2f[j] = frag_ld(B2s, wc * 32 + j * 16 + l15, ks, lhi);
            }
#pragma unroll
            for (int i = 0; i < 4; ++i)
#pragma unroll
                for (int j = 0; j < 2; ++j) {
                    acc1[i][j] = __builtin_amdgcn_mfma_f32_16x16x32_bf16(af[i], b1f[j], acc1[i][j], 0, 0, 0);
                    acc2[i][j] = __builtin_amdgcn_mfma_f32_16x16x32_bf16(af[i], b2f[j], acc2[i][j], 0, 0, 0);
                }
        }
    }
    __syncthreads();
#pragma unroll
    for (int i = 0; i < 4; ++i) {
        int mloc = wr * 64 + i * 16 + lhi * 4;
#pragma unroll
        for (int j = 0; j < 2; ++j) {
            int nloc = wc * 32 + j * 16 + l15;
            int n = n0 + nloc;
            float bb1 = b1[n], bb2 = b2[n];
#pragma unroll
            for (int q = 0; q < 4; ++q) {
                float a1 = acc1[i][j][q] + bb1;
                float a2 = acc2[i][j][q] + bb2;
                float hv = a1 / (1.0f + expf(-a1)) * a2;
                ((short*)As)[(mloc + q) * 64 + nloc] = f2bf(hv);
            }
        }
    }
    __syncthreads();
#pragma unroll
    for (int r = 0; r < 4; ++r) {
        int idx = tid + r * 256, row = idx >> 3, slot = idx & 7;
        *(bf16x8*)(h + (size_t)(m0 + row) * 512 + n0 + slot * 8) =
            *(const bf16x8*)((char*)As + row * 128 + slot * 16);
    }
}

// ================= FFN2 (MFMA, reg-prefetch): out = x1 + h @ W3 + b3 =================
__global__ __launch_bounds__(256) void k_ffn2(const short* __restrict__ h,
                                              const short* __restrict__ W3T, const float* __restrict__ b3,
                                              const float* __restrict__ x1,
                                              float* __restrict__ out) {
    __shared__ short As[64 * 64];
    __shared__ short Bs[128 * 64];
    int m0 = blockIdx.x * 64;
    int tid = threadIdx.x, lane = tid & 63, wid = tid >> 6;
    int l15 = lane & 15, lhi = lane >> 4;
    int wr = wid >> 1, wc = wid & 1;
    bf16x8 av[2], wv[4];
#pragma unroll
    for (int r = 0; r < 2; ++r) {
        int idx = tid + r * 256, row = idx >> 3, slot = idx & 7;
        av[r] = *(const bf16x8*)(h + (size_t)(m0 + row) * 512 + slot * 8);
    }
#pragma unroll
    for (int r = 0; r < 4; ++r) {
        int idx = tid + r * 256, row = idx >> 3, slot = idx & 7;
        wv[r] = *(const bf16x8*)(W3T + (size_t)row * 512 + slot * 8);
    }
    f32x4 acc[2][4] = {};
    for (int step = 0; step < 8; ++step) {
        __syncthreads();
#pragma unroll
        for (int r = 0; r < 2; ++r) {
            int idx = tid + r * 256, row = idx >> 3, slot = idx & 7;
            *(bf16x8*)((char*)As + row * 128 + ((slot * 16) ^ ((row & 7) << 4))) = av[r];
        }
#pragma unroll
        for (int r = 0; r < 4; ++r) {
            int idx = tid + r * 256, row = idx >> 3, slot = idx & 7;
            *(bf16x8*)((char*)Bs + row * 128 + ((slot * 16) ^ ((row & 7) << 4))) = wv[r];
        }
        __syncthreads();
        if (step < 7) {
            int k0 = (step + 1) * 64;
#pragma unroll
            for (int r = 0; r < 2; ++r) {
                int idx = tid + r * 256, row = idx >> 3, slot = idx & 7;
                av[r] = *(const bf16x8*)(h + (size_t)(m0 + row) * 512 + k0 + slot * 8);
            }
#pragma unroll
            for (int r = 0; r < 4; ++r) {
                int idx = tid + r * 256, row = idx >> 3, slot = idx & 7;
                wv[r] = *(const bf16x8*)(W3T + (size_t)row * 512 + k0 + slot * 8);
            }
        }
#pragma unroll
        for (int ks = 0; ks < 2; ++ks) {
            bf16x8 af[2], bfr[4];
#pragma unroll
            for (int i = 0; i < 2; ++i) af[i] = frag_ld(As, wr * 32 + i * 16 + l15, ks, lhi);
#pragma unroll
            for (int j = 0; j < 4; ++j) bfr[j] = frag_ld(Bs, wc * 64 + j * 16 + l15, ks, lhi);
#pragma unroll
            for (int i = 0; i < 2; ++i)
#pragma unroll
                for (int j = 0; j < 4; ++j)
                    acc[i][j] = __builtin_amdgcn_mfma_f32_16x16x32_bf16(af[i], bfr[j], acc[i][j], 0, 0, 0);
        }
    }
#pragma unroll
    for (int i = 0; i < 2; ++i) {
        int mbase = m0 + wr * 32 + i * 16 + lhi * 4;
#pragma unroll
        for (int j = 0; j < 4; ++j) {
            int n = wc * 64 + j * 16 + l15;
            float bv = b3[n];
#pragma unroll
            for (int q = 0; q < 4; ++q) {
                size_t off = (size_t)(mbase + q) * 128 + n;
                out[off] = acc[i][j][q] + x1[off] + bv;
            }
        }
    }
}

// ---- workspace layout (bytes) ----
constexpr size_t ALIGN_UP(size_t x) { return (x + 255) & ~(size_t)255; }
constexpr size_t SZ_X1   = ALIGN_UP((size_t)BN_ROWS * DIM_ * 4);       // f32
constexpr size_t SZ_RT   = ALIGN_UP((size_t)BN_ROWS * E_ * 4);         // f32
constexpr size_t SZ_A1   = ALIGN_UP((size_t)32 * 512 * 32 * 2);        // bf16
constexpr size_t SZ_A2   = ALIGN_UP((size_t)2 * 512 * 512 * 2);        // bf16
constexpr size_t SZ_XNT  = ALIGN_UP((size_t)B_ * 128 * 512 * 2);       // bf16
constexpr size_t SZ_YT   = ALIGN_UP((size_t)B_ * 128 * 1024 * 2);      // bf16
constexpr size_t SZ_XN2B = ALIGN_UP((size_t)BN_ROWS * DIM_ * 2);       // bf16
constexpr size_t SZ_H    = ALIGN_UP((size_t)BN_ROWS * HID_ * 2);       // bf16
constexpr size_t SZ_WT   = ALIGN_UP((size_t)128 * 512 * 2);            // bf16 (each)

extern "C" void kernel_launch(void* const* d_in, const int* in_sizes, int n_in,
                              void* d_out, int out_size, void* d_ws, size_t ws_size,
                              hipStream_t stream) {
    const float* x      = (const float*)d_in[0];
    const float* bias   = (const float*)d_in[1];
    const float* attn_s = (const float*)d_in[2];
    const float* ffn_s  = (const float*)d_in[3];
    const float* Wr     = (const float*)d_in[4];
    const float* br     = (const float*)d_in[5];
    const float* E1     = (const float*)d_in[6];
    const float* E2     = (const float*)d_in[7];
    const float* lq1    = (const float*)d_in[8];
    const float* lk1    = (const float*)d_in[9];
    const float* lq2    = (const float*)d_in[10];
    const float* lk2    = (const float*)d_in[11];
    // d_in[12] = outer_lambda: unused (outer mixing matrix == identity)
    const float* W1     = (const float*)d_in[13];
    const float* b1     = (const float*)d_in[14];
    const float* W2     = (const float*)d_in[15];
    const float* b2     = (const float*)d_in[16];
    const float* W3     = (const float*)d_in[17];
    const float* b3     = (const float*)d_in[18];

    char* p = (char*)d_ws;
    float* x1   = (float*)p;            p += SZ_X1;
    float* rt   = (float*)p;            p += SZ_RT;
    short* A1nb = (short*)p;            p += SZ_A1;
    short* A2nb = (short*)p;            p += SZ_A2;
    short* xnT  = (short*)p;            p += SZ_XNT;
    short* YT   = (short*)p;            p += SZ_YT;
    short* xn2b = (short*)p;            p += SZ_XN2B;
    short* h    = (short*)p;            p += SZ_H;
    short* W1T  = (short*)p;            p += SZ_WT;
    short* W2T  = (short*)p;            p += SZ_WT;
    short* W3T  = (short*)p;            p += SZ_WT;
    float* lam  = (float*)p;            p += 256;

    float* out_x   = (float*)d_out;
    float* out_idx = out_x + (size_t)BN_ROWS * DIM_;  // indices stored as float values

    float lam_init = 0.8f - 0.6f * expf(-0.3f);  // DEPTH = 1

    hipLaunchKernelGGL(k_misc, dim3(NMISC), dim3(256), 0, stream,
                       x, attn_s, Wr, br, bias, rt, out_idx, xnT,
                       E1, A1nb, E2, A2nb, W1, W2, W3, W1T, W2T, W3T,
                       lq1, lk1, lq2, lk2, lam_init, lam);
    hipLaunchKernelGGL(k_gemm_y, dim3(4, 128), dim3(256), 0, stream, A2nb, xnT, YT);
    hipLaunchKernelGGL(k_attn, dim3(8, 64), dim3(256), 0, stream, A1nb, rt, YT, x, lam, ffn_s, x1, xn2b);
    hipLaunchKernelGGL(k_ffn1, dim3(256, 8), dim3(256), 0, stream, xn2b, W1T, b1, W2T, b2, h);
    hipLaunchKernelGGL(k_ffn2, dim3(512), dim3(256), 0, stream, h, W3T, b3, x1, out_x);
}

// Round 6
// 199.539 us; speedup vs baseline: 3.0825x; 1.0654x over previous
//
#include <hip/hip_runtime.h>
#include <math.h>

#define B_ 64
#define N_ 512
#define DIM_ 128
#define E_ 16
#define G_ 32
#define TOPK_ 4
#define HID_ 512

constexpr int BN_ROWS = B_ * N_;  // 32768

using bf16x8 = __attribute__((ext_vector_type(8))) short;
using s16x4  = __attribute__((ext_vector_type(4))) short;
using f32x4  = __attribute__((ext_vector_type(4))) float;

__device__ __forceinline__ float bf2f(short s) {
    union { unsigned u; float f; } x;
    x.u = ((unsigned)(unsigned short)s) << 16;
    return x.f;
}
__device__ __forceinline__ short f2bf(float f) {
    union { float f; unsigned u; } x;
    x.f = f;
    unsigned r = x.u + 0x7FFF + ((x.u >> 16) & 1);  // RNE
    return (short)(r >> 16);
}

// read one MFMA fragment (8 bf16, 16B) from a [rows][64] bf16 LDS tile with XOR swizzle
__device__ __forceinline__ bf16x8 frag_ld(const short* base, int row, int ks, int lhi) {
    int addr = row * 128 + (((ks * 64) + lhi * 16) ^ ((row & 7) << 4));
    return *(const bf16x8*)((const char*)base + addr);
}

// ================= k_misc: all preprocessing in ONE launch, grid-sectioned =================
constexpr int NPRE = BN_ROWS / 4;     // 8192: fused rmsnorm+route (4 rows/block)
constexpr int NXNT = B_ * 16;         // 1024: fused rmsnorm+transpose -> xnT bf16 (32 rows/block)
constexpr int NSMG = 32 * 512 / 8;    // 2048: softmax over G
constexpr int NSMN = 1024 / 4;        // 256: softmax over N
constexpr int NTW  = 64 * 3;          // 192: weight transposes
constexpr int NMISC = NPRE + NXNT + NSMG + NSMN + NTW + 1;  // +1 lambda

__global__ __launch_bounds__(256) void k_misc(
    const float* __restrict__ x, const float* __restrict__ attn_s,
    const float* __restrict__ Wr, const float* __restrict__ br, const float* __restrict__ bias,
    float* __restrict__ route, float* __restrict__ topk_out,
    short* __restrict__ xnT,
    const float* __restrict__ E1, short* __restrict__ A1nb,
    const float* __restrict__ E2, short* __restrict__ A2nb,
    const float* __restrict__ W1, const float* __restrict__ W2, const float* __restrict__ W3,
    short* __restrict__ W1T, short* __restrict__ W2T, short* __restrict__ W3T,
    const float* __restrict__ lq1, const float* __restrict__ lk1,
    const float* __restrict__ lq2, const float* __restrict__ lk2,
    float lam_init, float* __restrict__ lam_out) {
    __shared__ float xbuf[4][132];
    __shared__ float tb[32][129];
    __shared__ float invb[32];
    __shared__ float tw[32][33];
    int blk = blockIdx.x;
    int tid = threadIdx.x;

    if (blk < NPRE) {  // ---- fused rmsnorm + route (rank-based top-k): wave = one row ----
        int w = tid >> 6, lane = tid & 63;
        int row = blk * 4 + w;
        float2 v = ((const float2*)(x + (size_t)row * DIM_))[lane];
        float ss = v.x * v.x + v.y * v.y;
        for (int off = 32; off; off >>= 1) ss += __shfl_xor(ss, off);
        float inv = 1.0f / (sqrtf(ss * (1.0f / DIM_)) + 1e-8f);
        float2 s = ((const float2*)attn_s)[lane];
        xbuf[w][lane * 2]     = v.x * inv * s.x;
        xbuf[w][lane * 2 + 1] = v.y * inv * s.y;
        // same wave produces & consumes xbuf[w] -> no barrier needed
        int e = lane & 15, chunk = lane >> 4;
        float acc = 0.f;
#pragma unroll
        for (int j = 0; j < 32; ++j) {
            int d = chunk * 32 + j;
            acc += xbuf[w][d] * Wr[d * E_ + e];
        }
        acc += __shfl_xor(acc, 16);
        acc += __shfl_xor(acc, 32);
        float gate = 1.0f / (1.0f + expf(-(acc + br[e])));
        float vv = gate + bias[0];
        // rank_e = #{i : v_i > v_e} + #{i < e : v_i == v_e}  (== lax.top_k order, ties -> lower idx)
        int rank = 0;
#pragma unroll
        for (int i = 0; i < 16; ++i) {
            float vi = __shfl(vv, i);
            rank += ((vi > vv) || (vi == vv && i < e)) ? 1 : 0;
        }
        bool selq = (rank < TOPK_) && (lane < 16);
        float contrib = selq ? gate : 0.f;
        float ssum = contrib;
        ssum += __shfl_xor(ssum, 1); ssum += __shfl_xor(ssum, 2);
        ssum += __shfl_xor(ssum, 4); ssum += __shfl_xor(ssum, 8);
        if (lane < 16) route[(size_t)row * E_ + e] = selq ? gate / ssum : 0.0f;
        if (selq) topk_out[(size_t)row * TOPK_ + rank] = (float)e;
        return;
    }
    blk -= NPRE;

    if (blk < NXNT) {  // ---- fused rmsnorm + transpose: xnT[b][c][j] bf16 ----
        int b = blk >> 4, j0 = (blk & 15) * 32;
        const float* src = x + (size_t)(b * 512 + j0) * 128;
        int r = tid >> 3, c8 = tid & 7;
#pragma unroll
        for (int it = 0; it < 4; ++it) {
            int c4 = c8 + it * 8;
            float4 w4 = *(const float4*)(src + (size_t)r * 128 + c4 * 4);
            tb[r][c4 * 4 + 0] = w4.x; tb[r][c4 * 4 + 1] = w4.y;
            tb[r][c4 * 4 + 2] = w4.z; tb[r][c4 * 4 + 3] = w4.w;
        }
        __syncthreads();
        int sg = tid & 7;
        float ps = 0.f;
#pragma unroll
        for (int j = 0; j < 16; ++j) { float e2 = tb[r][sg * 16 + j]; ps += e2 * e2; }
        ps += __shfl_xor(ps, 1); ps += __shfl_xor(ps, 2); ps += __shfl_xor(ps, 4);
        if (sg == 0) invb[r] = 1.0f / (sqrtf(ps * (1.0f / DIM_)) + 1e-8f);
        __syncthreads();
        int c = tid >> 1, half = tid & 1;
        float sc = attn_s[c];
        short ov[16];
#pragma unroll
        for (int j = 0; j < 16; ++j) {
            int jj = half * 16 + j;
            ov[j] = f2bf(tb[jj][c] * invb[jj] * sc);
        }
        short* dst = xnT + (size_t)(b * 128 + c) * 512 + j0 + half * 16;
        *(bf16x8*)dst = *(bf16x8*)ov;
        *(bf16x8*)(dst + 8) = *(bf16x8*)(ov + 8);
        return;
    }
    blk -= NXNT;

    if (blk < NSMG) {  // ---- softmax over G=32 -> bf16 ----
        int row = blk * 8 + (tid >> 5);
        int l = tid & 31;
        float v = E1[(size_t)row * 32 + l];
        float m = v;
        for (int off = 16; off; off >>= 1) m = fmaxf(m, __shfl_xor(m, off));
        float ev = expf(v - m);
        float s = ev;
        for (int off = 16; off; off >>= 1) s += __shfl_xor(s, off);
        A1nb[(size_t)row * 32 + l] = f2bf(ev / s);
        return;
    }
    blk -= NSMG;

    if (blk < NSMN) {  // ---- softmax over N=512 -> bf16 ----
        int row = blk * 4 + (tid >> 6);
        int l = tid & 63;
        const float* p = E2 + (size_t)row * 512;
        float v[8];
        float m = -1e30f;
#pragma unroll
        for (int j = 0; j < 8; ++j) { v[j] = p[l + j * 64]; m = fmaxf(m, v[j]); }
        for (int off = 32; off; off >>= 1) m = fmaxf(m, __shfl_xor(m, off));
        float s = 0.f;
#pragma unroll
        for (int j = 0; j < 8; ++j) { v[j] = expf(v[j] - m); s += v[j]; }
        for (int off = 32; off; off >>= 1) s += __shfl_xor(s, off);
        float inv = 1.0f / s;
        short* q = A2nb + (size_t)row * 512;
#pragma unroll
        for (int j = 0; j < 8; ++j) q[l + j * 64] = f2bf(v[j] * inv);
        return;
    }
    blk -= NSMN;

    if (blk < NTW) {  // ---- weight transposes -> bf16 [C][R] ----
        int m = blk >> 6, tile = blk & 63;
        const float* S = (m == 0) ? W1 : (m == 1) ? W2 : W3;
        short* D = (m == 0) ? W1T : (m == 1) ? W2T : W3T;
        int R = (m == 2) ? 512 : 128, C = (m == 2) ? 128 : 512;
        int ctiles = C / 32;
        int r0 = (tile / ctiles) * 32, c0 = (tile % ctiles) * 32;
        int tx = tid & 31, ty = tid >> 5;
#pragma unroll
        for (int r = 0; r < 4; ++r) tw[ty * 4 + r][tx] = S[(size_t)(r0 + ty * 4 + r) * C + c0 + tx];
        __syncthreads();
#pragma unroll
        for (int r = 0; r < 4; ++r) D[(size_t)(c0 + ty * 4 + r) * R + r0 + tx] = f2bf(tw[tx][ty * 4 + r]);
        return;
    }

    // ---- lambda (1 block, wave 0) ----
    if (tid < 64) {
        int l = tid;
        float s1 = lq1[l] * lk1[l] + lq1[l + 64] * lk1[l + 64];
        float s2 = lq2[l] * lk2[l] + lq2[l + 64] * lk2[l + 64];
        for (int off = 32; off; off >>= 1) {
            s1 += __shfl_xor(s1, off);
            s2 += __shfl_xor(s2, off);
        }
        if (l == 0) lam_out[0] = -(expf(s1) - expf(s2) + lam_init);
    }
}

// ================= Y-GEMM (MFMA, reg-prefetch, XCD-swizzled): YT[b][c][e*512+kd] =================
__global__ __launch_bounds__(256) void k_gemm_y(const short* __restrict__ A2nb,
                                                const short* __restrict__ xnT,
                                                short* __restrict__ YT) {
    __shared__ short As[128 * 64];
    __shared__ short Bs[128 * 64];
    // XCD-chunked swizzle: grid=512, consecutive nid (sharing b) land on the same XCD
    int id = blockIdx.x;
    int nid = ((id & 7) << 6) + (id >> 3);
    int m0 = (nid & 3) * 128;
    int be = nid >> 2, b = be >> 1, e = be & 1;
    int tid = threadIdx.x, lane = tid & 63, wid = tid >> 6;
    int l15 = lane & 15, lhi = lane >> 4;
    int wr = wid >> 1, wc = wid & 1;
    const short* Asrc = A2nb + (size_t)e * 512 * 512 + (size_t)m0 * 512;
    const short* Bsrc = xnT + (size_t)b * 128 * 512;
    bf16x8 av[4], bv[4];
#pragma unroll
    for (int r = 0; r < 4; ++r) {
        int idx = tid + r * 256, row = idx >> 3, slot = idx & 7;
        av[r] = *(const bf16x8*)(Asrc + (size_t)row * 512 + slot * 8);
        bv[r] = *(const bf16x8*)(Bsrc + (size_t)row * 512 + slot * 8);
    }
    f32x4 acc[4][4] = {};
    for (int step = 0; step < 8; ++step) {
        __syncthreads();
#pragma unroll
        for (int r = 0; r < 4; ++r) {
            int idx = tid + r * 256, row = idx >> 3, slot = idx & 7;
            *(bf16x8*)((char*)As + row * 128 + ((slot * 16) ^ ((row & 7) << 4))) = av[r];
            *(bf16x8*)((char*)Bs + row * 128 + ((slot * 16) ^ ((row & 7) << 4))) = bv[r];
        }
        __syncthreads();
        if (step < 7) {
            int k0 = (step + 1) * 64;
#pragma unroll
            for (int r = 0; r < 4; ++r) {
                int idx = tid + r * 256, row = idx >> 3, slot = idx & 7;
                av[r] = *(const bf16x8*)(Asrc + (size_t)row * 512 + k0 + slot * 8);
                bv[r] = *(const bf16x8*)(Bsrc + (size_t)row * 512 + k0 + slot * 8);
            }
        }
#pragma unroll
        for (int ks = 0; ks < 2; ++ks) {
            bf16x8 af[4], bfr[4];
#pragma unroll
            for (int i = 0; i < 4; ++i) af[i] = frag_ld(As, wr * 64 + i * 16 + l15, ks, lhi);
#pragma unroll
            for (int j = 0; j < 4; ++j) bfr[j] = frag_ld(Bs, wc * 64 + j * 16 + l15, ks, lhi);
#pragma unroll
            for (int i = 0; i < 4; ++i)
#pragma unroll
                for (int j = 0; j < 4; ++j)
                    acc[i][j] = __builtin_amdgcn_mfma_f32_16x16x32_bf16(af[i], bfr[j], acc[i][j], 0, 0, 0);
        }
    }
    short* Yb = YT + (size_t)b * 128 * 1024 + e * 512;
#pragma unroll
    for (int i = 0; i < 4; ++i) {
        int mbase = m0 + wr * 64 + i * 16 + lhi * 4;
#pragma unroll
        for (int j = 0; j < 4; ++j) {
            int n = wc * 64 + j * 16 + l15;
            s16x4 o;
#pragma unroll
            for (int q = 0; q < 4; ++q) o[q] = f2bf(acc[i][j][q]);
            *(s16x4*)(Yb + (size_t)n * 1024 + mbase) = o;
        }
    }
}

// ================= attn (MFMA, reg-prefetch, XCD-swizzled, fused residual + FFN rmsnorm) =================
__global__ __launch_bounds__(256) void k_attn(const short* __restrict__ A1nb,
                                              const float* __restrict__ route,
                                              const short* __restrict__ YT,
                                              const float* __restrict__ x,
                                              const float* __restrict__ lam_p,
                                              const float* __restrict__ ffn_s,
                                              float* __restrict__ x1,
                                              short* __restrict__ xn2b) {
    __shared__ short As[64 * 64];
    __shared__ short Bs[128 * 64];
    __shared__ float ssbuf[2][64];
    // XCD-chunked swizzle: grid=512, consecutive nid (sharing b -> YT[b] 256KB) on same XCD
    int id = blockIdx.x;
    int nid = ((id & 7) << 6) + (id >> 3);
    int m0 = (nid & 7) * 64;
    int b = nid >> 3;
    float lam = lam_p[0];
    int tid = threadIdx.x, lane = tid & 63, wid = tid >> 6;
    int l15 = lane & 15, lhi = lane >> 4;
    int wr = wid >> 1, wc = wid & 1;
    float rv[2];
    bf16x8 araw[2], yv[4];
#pragma unroll
    for (int r = 0; r < 2; ++r) {
        int idx = tid + r * 256, row = idx >> 3, slot = idx & 7;
        int t = (slot >> 2);
        int gi = m0 + row;
        rv[r] = route[((size_t)b * 512 + gi) * 16 + (t & 15)];  // t<16 at step 0
        araw[r] = *(const bf16x8*)(A1nb + ((size_t)t * 512 + gi) * 32 + (slot & 3) * 8);
    }
#pragma unroll
    for (int r = 0; r < 4; ++r) {
        int idx = tid + r * 256, row = idx >> 3, slot = idx & 7;
        yv[r] = *(const bf16x8*)(YT + ((size_t)b * 128 + row) * 1024 + slot * 8);
    }
    f32x4 acc[2][4] = {};
    for (int step = 0; step < 16; ++step) {
        __syncthreads();
#pragma unroll
        for (int r = 0; r < 2; ++r) {
            int idx = tid + r * 256, row = idx >> 3, slot = idx & 7;
            bf16x8 o;
#pragma unroll
            for (int q = 0; q < 8; ++q) o[q] = f2bf(bf2f(araw[r][q]) * rv[r]);
            *(bf16x8*)((char*)As + row * 128 + ((slot * 16) ^ ((row & 7) << 4))) = o;
        }
#pragma unroll
        for (int r = 0; r < 4; ++r) {
            int idx = tid + r * 256, row = idx >> 3, slot = idx & 7;
            *(bf16x8*)((char*)Bs + row * 128 + ((slot * 16) ^ ((row & 7) << 4))) = yv[r];
        }
        __syncthreads();
        if (step < 15) {
            int sn = step + 1;
#pragma unroll
            for (int r = 0; r < 2; ++r) {
                int idx = tid + r * 256, row = idx >> 3, slot = idx & 7;
                int t = sn * 2 + (slot >> 2);
                int gi = m0 + row;
                rv[r] = route[((size_t)b * 512 + gi) * 16 + (t & 15)] * (t >= 16 ? lam : 1.0f);
                araw[r] = *(const bf16x8*)(A1nb + ((size_t)t * 512 + gi) * 32 + (slot & 3) * 8);
            }
#pragma unroll
            for (int r = 0; r < 4; ++r) {
                int idx = tid + r * 256, row = idx >> 3, slot = idx & 7;
                yv[r] = *(const bf16x8*)(YT + ((size_t)b * 128 + row) * 1024 + sn * 64 + slot * 8);
            }
        }
#pragma unroll
        for (int ks = 0; ks < 2; ++ks) {
            bf16x8 af[2], bfr[4];
#pragma unroll
            for (int i = 0; i < 2; ++i) af[i] = frag_ld(As, wr * 32 + i * 16 + l15, ks, lhi);
#pragma unroll
            for (int j = 0; j < 4; ++j) bfr[j] = frag_ld(Bs, wc * 64 + j * 16 + l15, ks, lhi);
#pragma unroll
            for (int i = 0; i < 2; ++i)
#pragma unroll
                for (int j = 0; j < 4; ++j)
                    acc[i][j] = __builtin_amdgcn_mfma_f32_16x16x32_bf16(af[i], bfr[j], acc[i][j], 0, 0, 0);
        }
    }
    // epilogue: residual, write x1, fused rmsnorm -> xn2b
    float x1v[2][4][4];
    float pss[2][4] = {};
#pragma unroll
    for (int i = 0; i < 2; ++i) {
        int gibase = m0 + wr * 32 + i * 16 + lhi * 4;
#pragma unroll
        for (int j = 0; j < 4; ++j) {
            int n = wc * 64 + j * 16 + l15;
#pragma unroll
            for (int q = 0; q < 4; ++q) {
                size_t off = ((size_t)b * 512 + gibase + q) * 128 + n;
                float val = acc[i][j][q] + x[off];
                x1[off] = val;
                x1v[i][j][q] = val;
                pss[i][q] += val * val;
            }
        }
    }
#pragma unroll
    for (int i = 0; i < 2; ++i)
#pragma unroll
        for (int q = 0; q < 4; ++q) {
            float p = pss[i][q];
            p += __shfl_xor(p, 1); p += __shfl_xor(p, 2);
            p += __shfl_xor(p, 4); p += __shfl_xor(p, 8);
            pss[i][q] = p;
        }
    if (l15 == 0) {
#pragma unroll
        for (int i = 0; i < 2; ++i)
#pragma unroll
            for (int q = 0; q < 4; ++q)
                ssbuf[wc][wr * 32 + i * 16 + lhi * 4 + q] = pss[i][q];
    }
    __syncthreads();
#pragma unroll
    for (int i = 0; i < 2; ++i)
#pragma unroll
        for (int q = 0; q < 4; ++q) {
            int rowl = wr * 32 + i * 16 + lhi * 4 + q;
            float ssum = ssbuf[0][rowl] + ssbuf[1][rowl];
            float inv = 1.0f / (sqrtf(ssum * (1.0f / DIM_)) + 1e-8f);
#pragma unroll
            for (int j = 0; j < 4; ++j) {
                int n = wc * 64 + j * 16 + l15;
                xn2b[((size_t)b * 512 + m0 + rowl) * 128 + n] = f2bf(x1v[i][j][q] * inv * ffn_s[n]);
            }
        }
}

// ================= FFN1 (MFMA, reg-prefetch, XCD-swizzled, fused SwiGLU) =================
__global__ __launch_bounds__(256) void k_ffn1(const short* __restrict__ xn2b,
                                              const short* __restrict__ W1T, const float* __restrict__ b1,
                                              const short* __restrict__ W2T, const float* __restrict__ b2,
                                              short* __restrict__ h) {
    __shared__ short As[128 * 64];
    __shared__ short B1s[64 * 64];
    __shared__ short B2s[64 * 64];
    // XCD-chunked swizzle: grid=2048, consecutive nid (sharing m0 -> xn2b rows) on same XCD
    int id = blockIdx.x;
    int nid = ((id & 7) << 8) + (id >> 3);
    int n0 = (nid & 7) * 64;
    int m0 = (nid >> 3) * 128;
    int tid = threadIdx.x, lane = tid & 63, wid = tid >> 6;
    int l15 = lane & 15, lhi = lane >> 4;
    int wr = wid >> 1, wc = wid & 1;
    bf16x8 av[4], wv[4];
#pragma unroll
    for (int r = 0; r < 4; ++r) {
        int idx = tid + r * 256, row = idx >> 3, slot = idx & 7;
        av[r] = *(const bf16x8*)(xn2b + (size_t)(m0 + row) * 128 + slot * 8);
        int which = idx >> 9, brow = (idx >> 3) & 63;
        const short* S = which ? W2T : W1T;
        wv[r] = *(const bf16x8*)(S + (size_t)(n0 + brow) * 128 + slot * 8);
    }
    f32x4 acc1[4][2] = {}, acc2[4][2] = {};
    for (int step = 0; step < 2; ++step) {
        __syncthreads();
#pragma unroll
        for (int r = 0; r < 4; ++r) {
            int idx = tid + r * 256, row = idx >> 3, slot = idx & 7;
            *(bf16x8*)((char*)As + row * 128 + ((slot * 16) ^ ((row & 7) << 4))) = av[r];
            int which = idx >> 9, brow = (idx >> 3) & 63;
            short* D = which ? (short*)B2s : (short*)B1s;
            *(bf16x8*)((char*)D + brow * 128 + ((slot * 16) ^ ((brow & 7) << 4))) = wv[r];
        }
        __syncthreads();
        if (step == 0) {
#pragma unroll
            for (int r = 0; r < 4; ++r) {
                int idx = tid + r * 256, row = idx >> 3, slot = idx & 7;
                av[r] = *(const bf16x8*)(xn2b + (size_t)(m0 + row) * 128 + 64 + slot * 8);
                int which = idx >> 9, brow = (idx >> 3) & 63;
                const short* S = which ? W2T : W1T;
                wv[r] = *(const bf16x8*)(S + (size_t)(n0 + brow) * 128 + 64 + slot * 8);
            }
        }
#pragma unroll
        for (int ks = 0; ks < 2; ++ks) {
            bf16x8 af[4], b1f[2], b2f[2];
#pragma unroll
            for (int i = 0; i < 4; ++i) af[i] = frag_ld(As, wr * 64 + i * 16 + l15, ks, lhi);
#pragma unroll
            for (int j = 0; j < 2; ++j) {
                b1f[j] = frag_ld(B1s, wc * 32 + j * 16 + l15, ks, lhi);
                b2f[j] = frag_ld(B2s, wc * 32 + j * 16 + l15, ks, lhi);
            }
#pragma unroll
            for (int i = 0; i < 4; ++i)
#pragma unroll
                for (int j = 0; j < 2; ++j) {
                    acc1[i][j] = __builtin_amdgcn_mfma_f32_16x16x32_bf16(af[i], b1f[j], acc1[i][j], 0, 0, 0);
                    acc2[i][j] = __builtin_amdgcn_mfma_f32_16x16x32_bf16(af[i], b2f[j], acc2[i][j], 0, 0, 0);
                }
        }
    }
    __syncthreads();
#pragma unroll
    for (int i = 0; i < 4; ++i) {
        int mloc = wr * 64 + i * 16 + lhi * 4;
#pragma unroll
        for (int j = 0; j < 2; ++j) {
            int nloc = wc * 32 + j * 16 + l15;
            int n = n0 + nloc;
            float bb1 = b1[n], bb2 = b2[n];
#pragma unroll
            for (int q = 0; q < 4; ++q) {
                float a1 = acc1[i][j][q] + bb1;
                float a2 = acc2[i][j][q] + bb2;
                float hv = a1 / (1.0f + expf(-a1)) * a2;
                ((short*)As)[(mloc + q) * 64 + nloc] = f2bf(hv);
            }
        }
    }
    __syncthreads();
#pragma unroll
    for (int r = 0; r < 4; ++r) {
        int idx = tid + r * 256, row = idx >> 3, slot = idx & 7;
        *(bf16x8*)(h + (size_t)(m0 + row) * 512 + n0 + slot * 8) =
            *(const bf16x8*)((char*)As + row * 128 + slot * 16);
    }
}

// ================= FFN2 (MFMA, reg-prefetch): out = x1 + h @ W3 + b3 =================
__global__ __launch_bounds__(256) void k_ffn2(const short* __restrict__ h,
                                              const short* __restrict__ W3T, const float* __restrict__ b3,
                                              const float* __restrict__ x1,
                                              float* __restrict__ out) {
    __shared__ short As[64 * 64];
    __shared__ short Bs[128 * 64];
    int m0 = blockIdx.x * 64;
    int tid = threadIdx.x, lane = tid & 63, wid = tid >> 6;
    int l15 = lane & 15, lhi = lane >> 4;
    int wr = wid >> 1, wc = wid & 1;
    bf16x8 av[2], wv[4];
#pragma unroll
    for (int r = 0; r < 2; ++r) {
        int idx = tid + r * 256, row = idx >> 3, slot = idx & 7;
        av[r] = *(const bf16x8*)(h + (size_t)(m0 + row) * 512 + slot * 8);
    }
#pragma unroll
    for (int r = 0; r < 4; ++r) {
        int idx = tid + r * 256, row = idx >> 3, slot = idx & 7;
        wv[r] = *(const bf16x8*)(W3T + (size_t)row * 512 + slot * 8);
    }
    f32x4 acc[2][4] = {};
    for (int step = 0; step < 8; ++step) {
        __syncthreads();
#pragma unroll
        for (int r = 0; r < 2; ++r) {
            int idx = tid + r * 256, row = idx >> 3, slot = idx & 7;
            *(bf16x8*)((char*)As + row * 128 + ((slot * 16) ^ ((row & 7) << 4))) = av[r];
        }
#pragma unroll
        for (int r = 0; r < 4; ++r) {
            int idx = tid + r * 256, row = idx >> 3, slot = idx & 7;
            *(bf16x8*)((char*)Bs + row * 128 + ((slot * 16) ^ ((row & 7) << 4))) = wv[r];
        }
        __syncthreads();
        if (step < 7) {
            int k0 = (step + 1) * 64;
#pragma unroll
            for (int r = 0; r < 2; ++r) {
                int idx = tid + r * 256, row = idx >> 3, slot = idx & 7;
                av[r] = *(const bf16x8*)(h + (size_t)(m0 + row) * 512 + k0 + slot * 8);
            }
#pragma unroll
            for (int r = 0; r < 4; ++r) {
                int idx = tid + r * 256, row = idx >> 3, slot = idx & 7;
                wv[r] = *(const bf16x8*)(W3T + (size_t)row * 512 + k0 + slot * 8);
            }
        }
#pragma unroll
        for (int ks = 0; ks < 2; ++ks) {
            bf16x8 af[2], bfr[4];
#pragma unroll
            for (int i = 0; i < 2; ++i) af[i] = frag_ld(As, wr * 32 + i * 16 + l15, ks, lhi);
#pragma unroll
            for (int j = 0; j < 4; ++j) bfr[j] = frag_ld(Bs, wc * 64 + j * 16 + l15, ks, lhi);
#pragma unroll
            for (int i = 0; i < 2; ++i)
#pragma unroll
                for (int j = 0; j < 4; ++j)
                    acc[i][j] = __builtin_amdgcn_mfma_f32_16x16x32_bf16(af[i], bfr[j], acc[i][j], 0, 0, 0);
        }
    }
#pragma unroll
    for (int i = 0; i < 2; ++i) {
        int mbase = m0 + wr * 32 + i * 16 + lhi * 4;
#pragma unroll
        for (int j = 0; j < 4; ++j) {
            int n = wc * 64 + j * 16 + l15;
            float bv = b3[n];
#pragma unroll
            for (int q = 0; q < 4; ++q) {
                size_t off = (size_t)(mbase + q) * 128 + n;
                out[off] = acc[i][j][q] + x1[off] + bv;
            }
        }
    }
}

// ---- workspace layout (bytes) ----
constexpr size_t ALIGN_UP(size_t x) { return (x + 255) & ~(size_t)255; }
constexpr size_t SZ_X1   = ALIGN_UP((size_t)BN_ROWS * DIM_ * 4);       // f32
constexpr size_t SZ_RT   = ALIGN_UP((size_t)BN_ROWS * E_ * 4);         // f32
constexpr size_t SZ_A1   = ALIGN_UP((size_t)32 * 512 * 32 * 2);        // bf16
constexpr size_t SZ_A2   = ALIGN_UP((size_t)2 * 512 * 512 * 2);        // bf16
constexpr size_t SZ_XNT  = ALIGN_UP((size_t)B_ * 128 * 512 * 2);       // bf16
constexpr size_t SZ_YT   = ALIGN_UP((size_t)B_ * 128 * 1024 * 2);      // bf16
constexpr size_t SZ_XN2B = ALIGN_UP((size_t)BN_ROWS * DIM_ * 2);       // bf16
constexpr size_t SZ_H    = ALIGN_UP((size_t)BN_ROWS * HID_ * 2);       // bf16
constexpr size_t SZ_WT   = ALIGN_UP((size_t)128 * 512 * 2);            // bf16 (each)

extern "C" void kernel_launch(void* const* d_in, const int* in_sizes, int n_in,
                              void* d_out, int out_size, void* d_ws, size_t ws_size,
                              hipStream_t stream) {
    const float* x      = (const float*)d_in[0];
    const float* bias   = (const float*)d_in[1];
    const float* attn_s = (const float*)d_in[2];
    const float* ffn_s  = (const float*)d_in[3];
    const float* Wr     = (const float*)d_in[4];
    const float* br     = (const float*)d_in[5];
    const float* E1     = (const float*)d_in[6];
    const float* E2     = (const float*)d_in[7];
    const float* lq1    = (const float*)d_in[8];
    const float* lk1    = (const float*)d_in[9];
    const float* lq2    = (const float*)d_in[10];
    const float* lk2    = (const float*)d_in[11];
    // d_in[12] = outer_lambda: unused (outer mixing matrix == identity)
    const float* W1     = (const float*)d_in[13];
    const float* b1     = (const float*)d_in[14];
    const float* W2     = (const float*)d_in[15];
    const float* b2     = (const float*)d_in[16];
    const float* W3     = (const float*)d_in[17];
    const float* b3     = (const float*)d_in[18];

    char* p = (char*)d_ws;
    float* x1   = (float*)p;            p += SZ_X1;
    float* rt   = (float*)p;            p += SZ_RT;
    short* A1nb = (short*)p;            p += SZ_A1;
    short* A2nb = (short*)p;            p += SZ_A2;
    short* xnT  = (short*)p;            p += SZ_XNT;
    short* YT   = (short*)p;            p += SZ_YT;
    short* xn2b = (short*)p;            p += SZ_XN2B;
    short* h    = (short*)p;            p += SZ_H;
    short* W1T  = (short*)p;            p += SZ_WT;
    short* W2T  = (short*)p;            p += SZ_WT;
    short* W3T  = (short*)p;            p += SZ_WT;
    float* lam  = (float*)p;            p += 256;

    float* out_x   = (float*)d_out;
    float* out_idx = out_x + (size_t)BN_ROWS * DIM_;  // indices stored as float values

    float lam_init = 0.8f - 0.6f * expf(-0.3f);  // DEPTH = 1

    hipLaunchKernelGGL(k_misc, dim3(NMISC), dim3(256), 0, stream,
                       x, attn_s, Wr, br, bias, rt, out_idx, xnT,
                       E1, A1nb, E2, A2nb, W1, W2, W3, W1T, W2T, W3T,
                       lq1, lk1, lq2, lk2, lam_init, lam);
    hipLaunchKernelGGL(k_gemm_y, dim3(512), dim3(256), 0, stream, A2nb, xnT, YT);
    hipLaunchKernelGGL(k_attn, dim3(512), dim3(256), 0, stream, A1nb, rt, YT, x, lam, ffn_s, x1, xn2b);
    hipLaunchKernelGGL(k_ffn1, dim3(2048), dim3(256), 0, stream, xn2b, W1T, b1, W2T, b2, h);
    hipLaunchKernelGGL(k_ffn2, dim3(512), dim3(256), 0, stream, h, W3T, b3, x1, out_x);
}